// Round 1
// baseline (888.077 us; speedup 1.0000x reference)
//
#include <hip/hip_runtime.h>
#include <math.h>

static constexpr float PI2Q = 1.57079632679489662f; // 2*pi*Q, Q=0.25

// ---------------- head folding: w_eff[k] = sum_j Wc[j,k]*Wl[j]; w_eff[32] = bc@Wl + bl
__global__ void k_weff(const float* __restrict__ Wc, const float* __restrict__ bc,
                       const float* __restrict__ Wl, const float* __restrict__ bl,
                       float* __restrict__ weff) {
  int k = threadIdx.x;
  if (k < 32) {
    float s = 0.f;
    #pragma unroll
    for (int j = 0; j < 32; ++j) s += Wc[j * 32 + k] * Wl[j];
    weff[k] = s;
  } else if (k == 32) {
    float s = 0.f;
    for (int j = 0; j < 32; ++j) s += bc[j] * Wl[j];
    weff[32] = s + bl[0];
  }
}

// ---------------- embedding + layer-1 dense premultiplies
// h = (birth_e + gender_e + mean(symp_e))/3 (kept in registers)
// o0 = h@W1[0]+b1 ; PQ pairs: [p_f=h@W1[1], q_f=h@W1[2]]
__global__ __launch_bounds__(256) void k_embed(
    const int* __restrict__ x, const float* __restrict__ btab,
    const float* __restrict__ gtab, const float* __restrict__ stab,
    const float* __restrict__ W1, const float* __restrict__ b1,
    float* __restrict__ PQ, float* __restrict__ o0, int n) {
  __shared__ float sm[3184];
  // [0,1536) W1 ; [1536,1552) b1 ; [1552,1680) btab ; [1680,1744) gtab ; [1744,3184) stab
  int tid = threadIdx.x;
  for (int t = tid; t < 1536; t += 256) sm[t] = W1[t];
  if (tid < 16) sm[1536 + tid] = b1[tid];
  for (int t = tid; t < 128; t += 256) sm[1552 + t] = btab[t];
  for (int t = tid; t < 64; t += 256) sm[1680 + t] = gtab[t];
  for (int t = tid; t < 1440; t += 256) sm[1744 + t] = stab[t];
  __syncthreads();
  int i = blockIdx.x * 256 + tid;
  if (i >= n) return;
  int xr[20];
  #pragma unroll
  for (int j = 0; j < 20; ++j) xr[j] = x[i * 20 + j];
  int bi = 0;
  #pragma unroll
  for (int j = 3; j >= 0; --j) if (xr[j] == 1) bi = j;  // first match wins
  int g = xr[4];
  float h[32];
  #pragma unroll
  for (int f = 0; f < 32; ++f) {
    float s = 0.f;
    #pragma unroll
    for (int j = 0; j < 15; ++j) s += sm[1744 + j * 96 + xr[5 + j] * 32 + f];
    h[f] = (sm[1552 + bi * 32 + f] + sm[1680 + g * 32 + f] + s * (1.f / 15.f)) * (1.f / 3.f);
  }
  #pragma unroll
  for (int f = 0; f < 16; ++f) {
    float o = sm[1536 + f], p = 0.f, q = 0.f;
    #pragma unroll
    for (int k = 0; k < 32; ++k) {
      float hk = h[k];
      o = fmaf(hk, sm[k * 16 + f], o);
      p = fmaf(hk, sm[512 + k * 16 + f], p);
      q = fmaf(hk, sm[1024 + k * 16 + f], q);
    }
    o0[i * 16 + f] = o;
    PQ[i * 32 + 2 * f] = p;
    PQ[i * 32 + 2 * f + 1] = q;
  }
}

// ---------------- degree (weighted) + stub histogram
__global__ __launch_bounds__(256) void k_deg(const int* __restrict__ ei, const float* __restrict__ ew,
                                             float* __restrict__ deg, int* __restrict__ cnt, int E_) {
  int e = blockIdx.x * 256 + threadIdx.x;
  if (e >= E_) return;
  int s = ei[e], d = ei[E_ + e];
  float hw = 0.5f * ew[e];
  atomicAdd(&deg[s], hw);
  atomicAdd(&deg[d], hw);
  atomicAdd(&cnt[s], 1);
  atomicAdd(&cnt[d], 1);
}

__global__ __launch_bounds__(256) void k_dinv(float* __restrict__ deg, int n) {
  int i = blockIdx.x * 256 + threadIdx.x;
  if (i < n) { float d = deg[i]; deg[i] = (d > 0.f) ? rsqrtf(d) : 0.f; }
}

// ---------------- 3-kernel exclusive scan (cnt -> rowp)
__global__ __launch_bounds__(1024) void k_scan_a(const int* __restrict__ cnt, int* __restrict__ rowp,
                                                 int* __restrict__ bsum, int n) {
  __shared__ int sh[1024];
  int tid = threadIdx.x;
  int idx = blockIdx.x * 1024 + tid;
  int v = (idx < n) ? cnt[idx] : 0;
  sh[tid] = v;
  __syncthreads();
  for (int offd = 1; offd < 1024; offd <<= 1) {
    int t = (tid >= offd) ? sh[tid - offd] : 0;
    __syncthreads();
    sh[tid] += t;
    __syncthreads();
  }
  if (idx < n) rowp[idx] = sh[tid] - v;  // exclusive
  if (tid == 1023) bsum[blockIdx.x] = sh[1023];
}

__global__ __launch_bounds__(128) void k_scan_b(int* __restrict__ bsum, int nb,
                                                int* __restrict__ rowp, int n) {
  __shared__ int sh[128];
  int tid = threadIdx.x;
  int v = (tid < nb) ? bsum[tid] : 0;
  sh[tid] = v;
  __syncthreads();
  for (int offd = 1; offd < 128; offd <<= 1) {
    int t = (tid >= offd) ? sh[tid - offd] : 0;
    __syncthreads();
    sh[tid] += t;
    __syncthreads();
  }
  if (tid < nb) bsum[tid] = sh[tid] - v;  // exclusive block offsets
  if (tid == 127) rowp[n] = sh[127];      // grand total
}

__global__ __launch_bounds__(1024) void k_scan_c(int* __restrict__ rowp, const int* __restrict__ bsum, int n) {
  int idx = blockIdx.x * 1024 + threadIdx.x;
  if (idx < n && blockIdx.x > 0) rowp[idx] += bsum[blockIdx.x];
}

// ---------------- CSR fill: both stub directions of each edge
__global__ __launch_bounds__(256) void k_fill(const int* __restrict__ ei, const float* __restrict__ ew,
                                              const float* __restrict__ dinv, const int* __restrict__ rowp,
                                              int* __restrict__ fillc, int* __restrict__ srcs,
                                              float* __restrict__ areA, float* __restrict__ aimA, int E_) {
  int e = blockIdx.x * 256 + threadIdx.x;
  if (e >= E_) return;
  int s = ei[e], d = ei[E_ + e];
  float wgt = ew[e];
  float nrm = dinv[s] * (0.5f * wgt) * dinv[d];
  float sn, cs;
  sincosf(PI2Q * wgt, &sn, &cs);
  float ar = -nrm * cs;
  float ai = -nrm * sn;
  int pA = rowp[d] + atomicAdd(&fillc[d], 1);  // stub src->dst, theta=+
  srcs[pA] = s; areA[pA] = ar; aimA[pA] = ai;
  int pB = rowp[s] + atomicAdd(&fillc[s], 1);  // stub dst->src, theta=-
  srcs[pB] = d; areA[pB] = ar; aimA[pB] = -ai;
}

// ---------------- layer-1 hop 1 (xr==xi symmetry): one gather, 4 accumulators
// aA=t1r@W1[1], aB=t1i@W1[1] -> AB ; aC=ur, aD=ui (u=t1@W1[2]) -> U
__global__ __launch_bounds__(256) void k_hop_sym(
    const int* __restrict__ rowp, const int* __restrict__ srcs,
    const float* __restrict__ areA, const float* __restrict__ aimA,
    const float* __restrict__ PQ, float* __restrict__ U, float* __restrict__ AB, int n) {
  int wid = (blockIdx.x * 256 + threadIdx.x) >> 6;
  if (wid >= n) return;
  int lane = threadIdx.x & 63;
  int f = lane & 15, su = lane >> 4;
  int rs = rowp[wid], rend = rowp[wid + 1];
  float aA = 0.f, aB = 0.f, aC = 0.f, aD = 0.f;
  for (int k = rs + su; k < rend; k += 4) {
    int s = srcs[k];
    float ar = areA[k], ai = aimA[k];
    float wm = ar - ai, wp = ar + ai;
    float2 xv = *reinterpret_cast<const float2*>(PQ + s * 32 + 2 * f);
    aA = fmaf(wm, xv.x, aA);
    aB = fmaf(wp, xv.x, aB);
    aC = fmaf(wm, xv.y, aC);
    aD = fmaf(wp, xv.y, aD);
  }
  aA += __shfl_xor(aA, 16); aA += __shfl_xor(aA, 32);
  aB += __shfl_xor(aB, 16); aB += __shfl_xor(aB, 32);
  aC += __shfl_xor(aC, 16); aC += __shfl_xor(aC, 32);
  aD += __shfl_xor(aD, 16); aD += __shfl_xor(aD, 32);
  if (lane < 16) {
    *reinterpret_cast<float2*>(AB + wid * 32 + 2 * f) = make_float2(aA, aB);
    *reinterpret_cast<float2*>(U + wid * 32 + 2 * f) = make_float2(aC, aD);
  }
}

// ---------------- full complex hop. MODE 0: plain; 1: layer-1 epilogue -> X2; 2: final head -> y
template <int MODE>
__global__ __launch_bounds__(256) void k_hop_full(
    const int* __restrict__ rowp, const int* __restrict__ srcs,
    const float* __restrict__ areA, const float* __restrict__ aimA,
    const float* __restrict__ X, float* __restrict__ Y,
    const float* __restrict__ o0, const float* __restrict__ AB, const float* __restrict__ PQ,
    const float* __restrict__ D, const float* __restrict__ weff, int n) {
  int wid = (blockIdx.x * 256 + threadIdx.x) >> 6;
  if (wid >= n) return;
  int lane = threadIdx.x & 63;
  int f = lane & 15, su = lane >> 4;
  int rs = rowp[wid], rend = rowp[wid + 1];
  float aR = 0.f, aI = 0.f;
  for (int k = rs + su; k < rend; k += 4) {
    int s = srcs[k];
    float ar = areA[k], ai = aimA[k];
    float2 xv = *reinterpret_cast<const float2*>(X + s * 32 + 2 * f);
    aR = fmaf(ar, xv.x, aR); aR = fmaf(-ai, xv.y, aR);
    aI = fmaf(ar, xv.y, aI); aI = fmaf(ai, xv.x, aI);
  }
  aR += __shfl_xor(aR, 16); aR += __shfl_xor(aR, 32);
  aI += __shfl_xor(aI, 16); aI += __shfl_xor(aI, 32);
  if (MODE == 0) {
    if (lane < 16)
      *reinterpret_cast<float2*>(Y + wid * 32 + 2 * f) = make_float2(aR, aI);
  } else if (MODE == 1) {
    if (lane < 16) {
      float o = o0[wid * 16 + f];
      float2 ab = *reinterpret_cast<const float2*>(AB + wid * 32 + 2 * f);
      float q = PQ[wid * 32 + 2 * f + 1];
      *reinterpret_cast<float2*>(Y + wid * 32 + 2 * f) =
          make_float2(o + ab.x + 2.f * aR - q, o + ab.y + 2.f * aI - q);
    }
  } else {
    float c = 0.f;
    if (lane < 16) {
      float2 dv = *reinterpret_cast<const float2*>(D + wid * 32 + 2 * f);
      float zr = dv.x + 2.f * aR;
      float zi = dv.y + 2.f * aI;
      c = zr * weff[f] + zi * weff[16 + f];
    }
    c += __shfl_xor(c, 1); c += __shfl_xor(c, 2);
    c += __shfl_xor(c, 4); c += __shfl_xor(c, 8);
    if (lane == 0) Y[wid] = c + weff[32];
  }
}

// ---------------- layer-2 dense: U2 = t1'@W2[2] (complex) ; D = X2@(W2[0]-W2[2]) + t1'@W2[1] + b2
__global__ __launch_bounds__(256) void k_d2(const float* __restrict__ X2, const float* __restrict__ T1,
                                            const float* __restrict__ W2g, const float* __restrict__ b2g,
                                            float* __restrict__ U2, float* __restrict__ D, int n) {
  __shared__ float sm[1040];  // [0,768) W2 ; [768,784) b2 ; [784,1040) W2[0]-W2[2]
  int tid = threadIdx.x;
  for (int t = tid; t < 768; t += 256) sm[t] = W2g[t];
  if (tid < 16) sm[768 + tid] = b2g[tid];
  __syncthreads();
  if (tid < 256) sm[784 + tid] = sm[tid] - sm[512 + tid];
  __syncthreads();
  int i = blockIdx.x * 256 + tid;
  if (i >= n) return;
  float re[16], im[16], tr[16], ti[16];
  #pragma unroll
  for (int k = 0; k < 16; ++k) {
    float2 a = *reinterpret_cast<const float2*>(X2 + i * 32 + 2 * k);
    re[k] = a.x; im[k] = a.y;
    float2 b = *reinterpret_cast<const float2*>(T1 + i * 32 + 2 * k);
    tr[k] = b.x; ti[k] = b.y;
  }
  #pragma unroll
  for (int f = 0; f < 16; ++f) {
    float ur = 0.f, ui = 0.f;
    float dr = sm[768 + f], di = sm[768 + f];
    #pragma unroll
    for (int k = 0; k < 16; ++k) {
      float w2 = sm[512 + k * 16 + f];
      float w1 = sm[256 + k * 16 + f];
      float w02 = sm[784 + k * 16 + f];
      ur = fmaf(tr[k], w2, ur);
      ui = fmaf(ti[k], w2, ui);
      dr = fmaf(re[k], w02, dr); dr = fmaf(tr[k], w1, dr);
      di = fmaf(im[k], w02, di); di = fmaf(ti[k], w1, di);
    }
    *reinterpret_cast<float2*>(U2 + i * 32 + 2 * f) = make_float2(ur, ui);
    *reinterpret_cast<float2*>(D + i * 32 + 2 * f) = make_float2(dr, di);
  }
}

extern "C" void kernel_launch(void* const* d_in, const int* in_sizes, int n_in,
                              void* d_out, int out_size, void* d_ws, size_t ws_size,
                              hipStream_t stream) {
  const int* x = (const int*)d_in[0];
  const int* ei = (const int*)d_in[1];
  const float* ew = (const float*)d_in[2];
  const float* btab = (const float*)d_in[3];
  const float* gtab = (const float*)d_in[4];
  const float* stab = (const float*)d_in[5];
  const float* W1 = (const float*)d_in[6];
  const float* b1 = (const float*)d_in[7];
  const float* W2 = (const float*)d_in[8];
  const float* b2 = (const float*)d_in[9];
  const float* Wc = (const float*)d_in[10];
  const float* bc = (const float*)d_in[11];
  const float* Wl = (const float*)d_in[12];
  const float* bl = (const float*)d_in[13];
  float* yout = (float*)d_out;

  const int N_ = in_sizes[0] / 20;
  const int E_ = in_sizes[1] / 2;
  const int M_ = 2 * E_;

  size_t off = 0;
  auto take = [&](size_t bytes) -> void* {
    void* p = (char*)d_ws + off;
    off += (bytes + 255) & ~(size_t)255;
    return p;
  };
  float* PQ   = (float*)take((size_t)N_ * 32 * 4);  // pairs [p,q]; reused as U2
  float* o0   = (float*)take((size_t)N_ * 16 * 4);
  float* Ubuf = (float*)take((size_t)N_ * 32 * 4);  // U (hop1 out); reused as t1'
  float* ABuf = (float*)take((size_t)N_ * 32 * 4);  // AB (hop1 out); reused as D
  float* X2   = (float*)take((size_t)N_ * 32 * 4);  // layer-1 output pairs [re,im]
  float* deg  = (float*)take((size_t)N_ * 4);       // becomes dinv in-place
  int* cnt    = (int*)take((size_t)N_ * 4);
  int* fillc  = (int*)take((size_t)N_ * 4);
  int* rowp   = (int*)take((size_t)(N_ + 1) * 4);
  int* bsum   = (int*)take(1024 * 4);
  float* weff = (float*)take(64 * 4);
  int* srcs   = (int*)take((size_t)M_ * 4);
  float* areA = (float*)take((size_t)M_ * 4);
  float* aimA = (float*)take((size_t)M_ * 4);
  (void)ws_size; (void)n_in; (void)out_size;

  hipMemsetAsync(deg, 0, (size_t)N_ * 4, stream);
  hipMemsetAsync(cnt, 0, (size_t)N_ * 4, stream);
  hipMemsetAsync(fillc, 0, (size_t)N_ * 4, stream);

  int nbN = (N_ + 255) / 256;
  int nbE = (E_ + 255) / 256;
  int nbS = (N_ + 1023) / 1024;
  int nbH = (N_ + 3) / 4;  // one wave per node

  k_weff<<<1, 64, 0, stream>>>(Wc, bc, Wl, bl, weff);
  k_embed<<<nbN, 256, 0, stream>>>(x, btab, gtab, stab, W1, b1, PQ, o0, N_);
  k_deg<<<nbE, 256, 0, stream>>>(ei, ew, deg, cnt, E_);
  k_dinv<<<nbN, 256, 0, stream>>>(deg, N_);
  k_scan_a<<<nbS, 1024, 0, stream>>>(cnt, rowp, bsum, N_);
  k_scan_b<<<1, 128, 0, stream>>>(bsum, nbS, rowp, N_);
  k_scan_c<<<nbS, 1024, 0, stream>>>(rowp, bsum, N_);
  k_fill<<<nbE, 256, 0, stream>>>(ei, ew, deg, rowp, fillc, srcs, areA, aimA, E_);

  // layer 1
  k_hop_sym<<<nbH, 256, 0, stream>>>(rowp, srcs, areA, aimA, PQ, Ubuf, ABuf, N_);
  k_hop_full<1><<<nbH, 256, 0, stream>>>(rowp, srcs, areA, aimA, Ubuf, X2, o0, ABuf, PQ,
                                         nullptr, nullptr, N_);
  // layer 2
  k_hop_full<0><<<nbH, 256, 0, stream>>>(rowp, srcs, areA, aimA, X2, Ubuf, nullptr, nullptr,
                                         nullptr, nullptr, nullptr, N_);
  k_d2<<<nbN, 256, 0, stream>>>(X2, Ubuf, W2, b2, PQ, ABuf, N_);
  k_hop_full<2><<<nbH, 256, 0, stream>>>(rowp, srcs, areA, aimA, PQ, yout, nullptr, nullptr,
                                         nullptr, ABuf, weff, N_);
}

// Round 2
// 663.554 us; speedup vs baseline: 1.3384x; 1.3384x over previous
//
#include <hip/hip_runtime.h>
#include <math.h>

static constexpr float PI2Q = 1.57079632679489662f; // 2*pi*Q, Q=0.25

// ---------------- head folding: w_eff[k] = sum_j Wc[j,k]*Wl[j]; w_eff[32] = bc@Wl + bl
__global__ void k_weff(const float* __restrict__ Wc, const float* __restrict__ bc,
                       const float* __restrict__ Wl, const float* __restrict__ bl,
                       float* __restrict__ weff) {
  int k = threadIdx.x;
  if (k < 32) {
    float s = 0.f;
    #pragma unroll
    for (int j = 0; j < 32; ++j) s += Wc[j * 32 + k] * Wl[j];
    weff[k] = s;
  } else if (k == 32) {
    float s = 0.f;
    for (int j = 0; j < 32; ++j) s += bc[j] * Wl[j];
    weff[32] = s + bl[0];
  }
}

// ---------------- embedding + layer-1 dense premultiplies
__global__ __launch_bounds__(256) void k_embed(
    const int* __restrict__ x, const float* __restrict__ btab,
    const float* __restrict__ gtab, const float* __restrict__ stab,
    const float* __restrict__ W1, const float* __restrict__ b1,
    float* __restrict__ PQ, float* __restrict__ o0, int n) {
  __shared__ float sm[3184];
  // [0,1536) W1 ; [1536,1552) b1 ; [1552,1680) btab ; [1680,1744) gtab ; [1744,3184) stab
  int tid = threadIdx.x;
  for (int t = tid; t < 1536; t += 256) sm[t] = W1[t];
  if (tid < 16) sm[1536 + tid] = b1[tid];
  for (int t = tid; t < 128; t += 256) sm[1552 + t] = btab[t];
  for (int t = tid; t < 64; t += 256) sm[1680 + t] = gtab[t];
  for (int t = tid; t < 1440; t += 256) sm[1744 + t] = stab[t];
  __syncthreads();
  int i = blockIdx.x * 256 + tid;
  if (i >= n) return;
  int xr[20];
  #pragma unroll
  for (int j = 0; j < 20; ++j) xr[j] = x[i * 20 + j];
  int bi = 0;
  #pragma unroll
  for (int j = 3; j >= 0; --j) if (xr[j] == 1) bi = j;  // first match wins
  int g = xr[4];
  float h[32];
  #pragma unroll
  for (int f = 0; f < 32; ++f) {
    float s = 0.f;
    #pragma unroll
    for (int j = 0; j < 15; ++j) s += sm[1744 + j * 96 + xr[5 + j] * 32 + f];
    h[f] = (sm[1552 + bi * 32 + f] + sm[1680 + g * 32 + f] + s * (1.f / 15.f)) * (1.f / 3.f);
  }
  #pragma unroll
  for (int f = 0; f < 16; ++f) {
    float o = sm[1536 + f], p = 0.f, q = 0.f;
    #pragma unroll
    for (int k = 0; k < 32; ++k) {
      float hk = h[k];
      o = fmaf(hk, sm[k * 16 + f], o);
      p = fmaf(hk, sm[512 + k * 16 + f], p);
      q = fmaf(hk, sm[1024 + k * 16 + f], q);
    }
    o0[i * 16 + f] = o;
    PQ[i * 32 + 2 * f] = p;
    PQ[i * 32 + 2 * f + 1] = q;
  }
}

// ---------------- stub histogram; the returned old count IS the stub's rank in its row
__global__ __launch_bounds__(256) void k_cnt(const int* __restrict__ ei, int* __restrict__ cnt,
                                             int* __restrict__ ranks, int E_) {
  int e = blockIdx.x * 256 + threadIdx.x;
  if (e >= E_) return;
  int s = ei[e], d = ei[E_ + e];
  ranks[e] = atomicAdd(&cnt[d], 1);       // stub s->d lives in row d
  ranks[E_ + e] = atomicAdd(&cnt[s], 1);  // stub d->s lives in row s
}

// ---------------- 3-kernel exclusive scan (cnt -> rowp)
__global__ __launch_bounds__(1024) void k_scan_a(const int* __restrict__ cnt, int* __restrict__ rowp,
                                                 int* __restrict__ bsum, int n) {
  __shared__ int sh[1024];
  int tid = threadIdx.x;
  int idx = blockIdx.x * 1024 + tid;
  int v = (idx < n) ? cnt[idx] : 0;
  sh[tid] = v;
  __syncthreads();
  for (int offd = 1; offd < 1024; offd <<= 1) {
    int t = (tid >= offd) ? sh[tid - offd] : 0;
    __syncthreads();
    sh[tid] += t;
    __syncthreads();
  }
  if (idx < n) rowp[idx] = sh[tid] - v;  // exclusive
  if (tid == 1023) bsum[blockIdx.x] = sh[1023];
}

__global__ __launch_bounds__(128) void k_scan_b(int* __restrict__ bsum, int nb,
                                                int* __restrict__ rowp, int n) {
  __shared__ int sh[128];
  int tid = threadIdx.x;
  int v = (tid < nb) ? bsum[tid] : 0;
  sh[tid] = v;
  __syncthreads();
  for (int offd = 1; offd < 128; offd <<= 1) {
    int t = (tid >= offd) ? sh[tid - offd] : 0;
    __syncthreads();
    sh[tid] += t;
    __syncthreads();
  }
  if (tid < nb) bsum[tid] = sh[tid] - v;  // exclusive block offsets
  if (tid == 127) rowp[n] = sh[127];      // grand total
}

__global__ __launch_bounds__(1024) void k_scan_c(int* __restrict__ rowp, const int* __restrict__ bsum, int n) {
  int idx = blockIdx.x * 1024 + threadIdx.x;
  if (idx < n && blockIdx.x > 0) rowp[idx] += bsum[blockIdx.x];
}

// ---------------- CSR fill, atomic-free: pos = rowp[row] + rank
// record: {src | dir<<31, edge_weight}
__global__ __launch_bounds__(256) void k_fill(const int* __restrict__ ei, const float* __restrict__ ew,
                                              const int* __restrict__ rowp, const int* __restrict__ ranks,
                                              int2* __restrict__ recs, int E_) {
  int e = blockIdx.x * 256 + threadIdx.x;
  if (e >= E_) return;
  int s = ei[e], d = ei[E_ + e];
  int wbits = __float_as_int(ew[e]);
  int pA = rowp[d] + ranks[e];
  recs[pA] = make_int2(s, wbits);                              // theta = +
  int pB = rowp[s] + ranks[E_ + e];
  recs[pB] = make_int2(d | (int)0x80000000, wbits);            // theta = -
}

// ---------------- weighted degree from CSR rows (no atomics) -> dinv
__global__ __launch_bounds__(256) void k_rowdeg(const int* __restrict__ rowp, const int2* __restrict__ recs,
                                                float* __restrict__ dinv, int n) {
  int wid = (blockIdx.x * 256 + threadIdx.x) >> 6;
  if (wid >= n) return;
  int lane = threadIdx.x & 63;
  int rs = rowp[wid], re = rowp[wid + 1];
  float sum = 0.f;
  for (int k = rs + lane; k < re; k += 64) sum += __int_as_float(recs[k].y);
  sum += __shfl_xor(sum, 1); sum += __shfl_xor(sum, 2);
  sum += __shfl_xor(sum, 4); sum += __shfl_xor(sum, 8);
  sum += __shfl_xor(sum, 16); sum += __shfl_xor(sum, 32);
  if (lane == 0) {
    float dg = 0.5f * sum;
    dinv[wid] = (dg > 0.f) ? rsqrtf(dg) : 0.f;
  }
}

// ---------------- per-stub normalization + phase (sequential writes)
__global__ __launch_bounds__(256) void k_norm(const int* __restrict__ rowp, const int2* __restrict__ recs,
                                              const float* __restrict__ dinv, int* __restrict__ srcs,
                                              float2* __restrict__ aw, int n) {
  int wid = (blockIdx.x * 256 + threadIdx.x) >> 6;
  if (wid >= n) return;
  int lane = threadIdx.x & 63;
  float di = dinv[wid];
  int rs = rowp[wid], re = rowp[wid + 1];
  for (int k = rs + lane; k < re; k += 64) {
    int2 r = recs[k];
    int s = r.x & 0x7fffffff;
    float w = __int_as_float(r.y);
    float nrm = di * 0.5f * w * dinv[s];
    float sn, cs;
    sincosf(PI2Q * w, &sn, &cs);
    float ar = -nrm * cs;
    float ai = (r.x < 0) ? nrm * sn : -nrm * sn;
    srcs[k] = s;
    aw[k] = make_float2(ar, ai);
  }
}

// ---------------- layer-1 hop 1 (xr==xi symmetry): one gather, 4 accumulators
__global__ __launch_bounds__(256) void k_hop_sym(
    const int* __restrict__ rowp, const int* __restrict__ srcs, const float2* __restrict__ aw,
    const float* __restrict__ PQ, float* __restrict__ U, float* __restrict__ AB, int n) {
  int wid = (blockIdx.x * 256 + threadIdx.x) >> 6;
  if (wid >= n) return;
  int lane = threadIdx.x & 63;
  int f = lane & 15, su = lane >> 4;
  int rs = rowp[wid], rend = rowp[wid + 1];
  float aA = 0.f, aB = 0.f, aC = 0.f, aD = 0.f;
  for (int k = rs + su; k < rend; k += 4) {
    int s = srcs[k];
    float2 a = aw[k];
    float wm = a.x - a.y, wp = a.x + a.y;
    float2 xv = *reinterpret_cast<const float2*>(PQ + s * 32 + 2 * f);
    aA = fmaf(wm, xv.x, aA);
    aB = fmaf(wp, xv.x, aB);
    aC = fmaf(wm, xv.y, aC);
    aD = fmaf(wp, xv.y, aD);
  }
  aA += __shfl_xor(aA, 16); aA += __shfl_xor(aA, 32);
  aB += __shfl_xor(aB, 16); aB += __shfl_xor(aB, 32);
  aC += __shfl_xor(aC, 16); aC += __shfl_xor(aC, 32);
  aD += __shfl_xor(aD, 16); aD += __shfl_xor(aD, 32);
  if (lane < 16) {
    *reinterpret_cast<float2*>(AB + wid * 32 + 2 * f) = make_float2(aA, aB);
    *reinterpret_cast<float2*>(U + wid * 32 + 2 * f) = make_float2(aC, aD);
  }
}

// ---------------- full complex hop. MODE 0: plain; 1: layer-1 epilogue -> X2; 2: final head -> y
template <int MODE>
__global__ __launch_bounds__(256) void k_hop_full(
    const int* __restrict__ rowp, const int* __restrict__ srcs, const float2* __restrict__ aw,
    const float* __restrict__ X, float* __restrict__ Y,
    const float* __restrict__ o0, const float* __restrict__ AB, const float* __restrict__ PQ,
    const float* __restrict__ D, const float* __restrict__ weff, int n) {
  int wid = (blockIdx.x * 256 + threadIdx.x) >> 6;
  if (wid >= n) return;
  int lane = threadIdx.x & 63;
  int f = lane & 15, su = lane >> 4;
  int rs = rowp[wid], rend = rowp[wid + 1];
  float aR = 0.f, aI = 0.f;
  for (int k = rs + su; k < rend; k += 4) {
    int s = srcs[k];
    float2 a = aw[k];
    float2 xv = *reinterpret_cast<const float2*>(X + s * 32 + 2 * f);
    aR = fmaf(a.x, xv.x, aR); aR = fmaf(-a.y, xv.y, aR);
    aI = fmaf(a.x, xv.y, aI); aI = fmaf(a.y, xv.x, aI);
  }
  aR += __shfl_xor(aR, 16); aR += __shfl_xor(aR, 32);
  aI += __shfl_xor(aI, 16); aI += __shfl_xor(aI, 32);
  if (MODE == 0) {
    if (lane < 16)
      *reinterpret_cast<float2*>(Y + wid * 32 + 2 * f) = make_float2(aR, aI);
  } else if (MODE == 1) {
    if (lane < 16) {
      float o = o0[wid * 16 + f];
      float2 ab = *reinterpret_cast<const float2*>(AB + wid * 32 + 2 * f);
      float q = PQ[wid * 32 + 2 * f + 1];
      *reinterpret_cast<float2*>(Y + wid * 32 + 2 * f) =
          make_float2(o + ab.x + 2.f * aR - q, o + ab.y + 2.f * aI - q);
    }
  } else {
    float c = 0.f;
    if (lane < 16) {
      float2 dv = *reinterpret_cast<const float2*>(D + wid * 32 + 2 * f);
      float zr = dv.x + 2.f * aR;
      float zi = dv.y + 2.f * aI;
      c = zr * weff[f] + zi * weff[16 + f];
    }
    c += __shfl_xor(c, 1); c += __shfl_xor(c, 2);
    c += __shfl_xor(c, 4); c += __shfl_xor(c, 8);
    if (lane == 0) Y[wid] = c + weff[32];
  }
}

// ---------------- layer-2 dense: U2 = t1'@W2[2] (complex) ; D = X2@(W2[0]-W2[2]) + t1'@W2[1] + b2
__global__ __launch_bounds__(256) void k_d2(const float* __restrict__ X2, const float* __restrict__ T1,
                                            const float* __restrict__ W2g, const float* __restrict__ b2g,
                                            float* __restrict__ U2, float* __restrict__ D, int n) {
  __shared__ float sm[1040];  // [0,768) W2 ; [768,784) b2 ; [784,1040) W2[0]-W2[2]
  int tid = threadIdx.x;
  for (int t = tid; t < 768; t += 256) sm[t] = W2g[t];
  if (tid < 16) sm[768 + tid] = b2g[tid];
  __syncthreads();
  if (tid < 256) sm[784 + tid] = sm[tid] - sm[512 + tid];
  __syncthreads();
  int i = blockIdx.x * 256 + tid;
  if (i >= n) return;
  float re[16], im[16], tr[16], ti[16];
  #pragma unroll
  for (int k = 0; k < 16; ++k) {
    float2 a = *reinterpret_cast<const float2*>(X2 + i * 32 + 2 * k);
    re[k] = a.x; im[k] = a.y;
    float2 b = *reinterpret_cast<const float2*>(T1 + i * 32 + 2 * k);
    tr[k] = b.x; ti[k] = b.y;
  }
  #pragma unroll
  for (int f = 0; f < 16; ++f) {
    float ur = 0.f, ui = 0.f;
    float dr = sm[768 + f], di = sm[768 + f];
    #pragma unroll
    for (int k = 0; k < 16; ++k) {
      float w2 = sm[512 + k * 16 + f];
      float w1 = sm[256 + k * 16 + f];
      float w02 = sm[784 + k * 16 + f];
      ur = fmaf(tr[k], w2, ur);
      ui = fmaf(ti[k], w2, ui);
      dr = fmaf(re[k], w02, dr); dr = fmaf(tr[k], w1, dr);
      di = fmaf(im[k], w02, di); di = fmaf(ti[k], w1, di);
    }
    *reinterpret_cast<float2*>(U2 + i * 32 + 2 * f) = make_float2(ur, ui);
    *reinterpret_cast<float2*>(D + i * 32 + 2 * f) = make_float2(dr, di);
  }
}

extern "C" void kernel_launch(void* const* d_in, const int* in_sizes, int n_in,
                              void* d_out, int out_size, void* d_ws, size_t ws_size,
                              hipStream_t stream) {
  const int* x = (const int*)d_in[0];
  const int* ei = (const int*)d_in[1];
  const float* ew = (const float*)d_in[2];
  const float* btab = (const float*)d_in[3];
  const float* gtab = (const float*)d_in[4];
  const float* stab = (const float*)d_in[5];
  const float* W1 = (const float*)d_in[6];
  const float* b1 = (const float*)d_in[7];
  const float* W2 = (const float*)d_in[8];
  const float* b2 = (const float*)d_in[9];
  const float* Wc = (const float*)d_in[10];
  const float* bc = (const float*)d_in[11];
  const float* Wl = (const float*)d_in[12];
  const float* bl = (const float*)d_in[13];
  float* yout = (float*)d_out;

  const int N_ = in_sizes[0] / 20;
  const int E_ = in_sizes[1] / 2;
  const int M_ = 2 * E_;

  size_t off = 0;
  auto take = [&](size_t bytes) -> void* {
    void* p = (char*)d_ws + off;
    off += (bytes + 255) & ~(size_t)255;
    return p;
  };
  float* PQ   = (float*)take((size_t)N_ * 32 * 4);  // pairs [p,q]; reused as U2
  float* o0   = (float*)take((size_t)N_ * 16 * 4);
  float* Ubuf = (float*)take((size_t)N_ * 32 * 4);  // overlay: recs8 (first half)
  float* ABuf = (float*)take((size_t)N_ * 32 * 4);  // overlay: recs8 (second half)
  float* X2   = (float*)take((size_t)N_ * 32 * 4);  // overlay: ranks
  float* dinv = (float*)take((size_t)N_ * 4);
  int* cnt    = (int*)take((size_t)N_ * 4);
  int* rowp   = (int*)take((size_t)(N_ + 1) * 4);
  int* bsum   = (int*)take(1024 * 4);
  float* weff = (float*)take(64 * 4);
  int* srcs   = (int*)take((size_t)M_ * 4);
  float2* aw  = (float2*)take((size_t)M_ * 8);
  (void)ws_size; (void)n_in; (void)out_size;

  // Overlays (lifetimes disjoint on the single stream):
  //  ranks: lives [k_cnt .. k_fill); X2 first written by hop_full<1> (later).  12.8MB == N*32*4.
  //  recs8: lives [k_fill .. k_norm); Ubuf/ABuf first written by k_hop_sym (later). 25.6MB == 2*N*32*4.
  int* ranks = (int*)X2;
  int2* recs = (int2*)Ubuf;

  hipMemsetAsync(cnt, 0, (size_t)N_ * 4, stream);

  int nbN = (N_ + 255) / 256;
  int nbE = (E_ + 255) / 256;
  int nbS = (N_ + 1023) / 1024;
  int nbH = (N_ + 3) / 4;  // one wave per node

  k_weff<<<1, 64, 0, stream>>>(Wc, bc, Wl, bl, weff);
  k_embed<<<nbN, 256, 0, stream>>>(x, btab, gtab, stab, W1, b1, PQ, o0, N_);
  k_cnt<<<nbE, 256, 0, stream>>>(ei, cnt, ranks, E_);
  k_scan_a<<<nbS, 1024, 0, stream>>>(cnt, rowp, bsum, N_);
  k_scan_b<<<1, 128, 0, stream>>>(bsum, nbS, rowp, N_);
  k_scan_c<<<nbS, 1024, 0, stream>>>(rowp, bsum, N_);
  k_fill<<<nbE, 256, 0, stream>>>(ei, ew, rowp, ranks, recs, E_);
  k_rowdeg<<<nbH, 256, 0, stream>>>(rowp, recs, dinv, N_);
  k_norm<<<nbH, 256, 0, stream>>>(rowp, recs, dinv, srcs, aw, N_);

  // layer 1
  k_hop_sym<<<nbH, 256, 0, stream>>>(rowp, srcs, aw, PQ, Ubuf, ABuf, N_);
  k_hop_full<1><<<nbH, 256, 0, stream>>>(rowp, srcs, aw, Ubuf, X2, o0, ABuf, PQ,
                                         nullptr, nullptr, N_);
  // layer 2
  k_hop_full<0><<<nbH, 256, 0, stream>>>(rowp, srcs, aw, X2, Ubuf, nullptr, nullptr,
                                         nullptr, nullptr, nullptr, N_);
  k_d2<<<nbN, 256, 0, stream>>>(X2, Ubuf, W2, b2, PQ, ABuf, N_);
  k_hop_full<2><<<nbH, 256, 0, stream>>>(rowp, srcs, aw, PQ, yout, nullptr, nullptr,
                                         nullptr, ABuf, weff, N_);
}

// Round 3
// 608.276 us; speedup vs baseline: 1.4600x; 1.0909x over previous
//
#include <hip/hip_runtime.h>
#include <math.h>

static constexpr float PI2Q = 1.57079632679489662f; // 2*pi*Q, Q=0.25
#define NRANGE 8
#define NSTRIPE 64
#define MAXRNG 13056  // LDS histogram capacity (ints); N/8 must be <= this

// ---------------- head folding: w_eff[k] = sum_j Wc[j,k]*Wl[j]; w_eff[32] = bc@Wl + bl
__global__ void k_weff(const float* __restrict__ Wc, const float* __restrict__ bc,
                       const float* __restrict__ Wl, const float* __restrict__ bl,
                       float* __restrict__ weff) {
  int k = threadIdx.x;
  if (k < 32) {
    float s = 0.f;
    #pragma unroll
    for (int j = 0; j < 32; ++j) s += Wc[j * 32 + k] * Wl[j];
    weff[k] = s;
  } else if (k == 32) {
    float s = 0.f;
    for (int j = 0; j < 32; ++j) s += bc[j] * Wl[j];
    weff[32] = s + bl[0];
  }
}

// ---------------- embedding + layer-1 dense premultiplies
__global__ __launch_bounds__(256) void k_embed(
    const int* __restrict__ x, const float* __restrict__ btab,
    const float* __restrict__ gtab, const float* __restrict__ stab,
    const float* __restrict__ W1, const float* __restrict__ b1,
    float* __restrict__ PQ, float* __restrict__ o0, int n) {
  __shared__ float sm[3184];
  // [0,1536) W1 ; [1536,1552) b1 ; [1552,1680) btab ; [1680,1744) gtab ; [1744,3184) stab
  int tid = threadIdx.x;
  for (int t = tid; t < 1536; t += 256) sm[t] = W1[t];
  if (tid < 16) sm[1536 + tid] = b1[tid];
  for (int t = tid; t < 128; t += 256) sm[1552 + t] = btab[t];
  for (int t = tid; t < 64; t += 256) sm[1680 + t] = gtab[t];
  for (int t = tid; t < 1440; t += 256) sm[1744 + t] = stab[t];
  __syncthreads();
  int i = blockIdx.x * 256 + tid;
  if (i >= n) return;
  int xr[20];
  #pragma unroll
  for (int j = 0; j < 20; ++j) xr[j] = x[i * 20 + j];
  int bi = 0;
  #pragma unroll
  for (int j = 3; j >= 0; --j) if (xr[j] == 1) bi = j;  // first match wins
  int g = xr[4];
  float h[32];
  #pragma unroll
  for (int f = 0; f < 32; ++f) {
    float s = 0.f;
    #pragma unroll
    for (int j = 0; j < 15; ++j) s += sm[1744 + j * 96 + xr[5 + j] * 32 + f];
    h[f] = (sm[1552 + bi * 32 + f] + sm[1680 + g * 32 + f] + s * (1.f / 15.f)) * (1.f / 3.f);
  }
  #pragma unroll
  for (int f = 0; f < 16; ++f) {
    float o = sm[1536 + f], p = 0.f, q = 0.f;
    #pragma unroll
    for (int k = 0; k < 32; ++k) {
      float hk = h[k];
      o = fmaf(hk, sm[k * 16 + f], o);
      p = fmaf(hk, sm[512 + k * 16 + f], p);
      q = fmaf(hk, sm[1024 + k * 16 + f], q);
    }
    o0[i * 16 + f] = o;
    PQ[i * 32 + 2 * f] = p;
    PQ[i * 32 + 2 * f + 1] = q;
  }
}

// ---------------- pass1: per-(range,stripe) LDS histogram of stub rows
__global__ __launch_bounds__(1024) void k_hist(const int* __restrict__ ei, int* __restrict__ Hg,
                                               int rng, int E_, int slen) {
  __shared__ int hist[MAXRNG];
  int r = blockIdx.x & (NRANGE - 1);
  int st = blockIdx.x >> 3;  // log2(NRANGE)
  int base = r * rng;
  int tid = threadIdx.x;
  for (int t = tid; t < rng; t += 1024) hist[t] = 0;
  __syncthreads();
  int e0 = st * slen;
  int e1 = min(E_, e0 + slen);
  for (int e = e0 + tid; e < e1; e += 1024) {
    int s = ei[e], d = ei[E_ + e];
    unsigned dloc = (unsigned)(d - base), sloc = (unsigned)(s - base);
    if (dloc < (unsigned)rng) atomicAdd(&hist[dloc], 1);
    if (sloc < (unsigned)rng) atomicAdd(&hist[sloc], 1);
  }
  __syncthreads();
  int* plane = Hg + (size_t)(r * NSTRIPE + st) * rng;
  for (int t = tid; t < rng; t += 1024) plane[t] = hist[t];
}

// ---------------- scanH: per node, exclusive prefix across the 64 stripes; total -> cnt
__global__ __launch_bounds__(512) void k_scanH(int* __restrict__ Hg, int* __restrict__ cnt,
                                               int rng, int n) {
  int v = blockIdx.x * 512 + threadIdx.x;
  if (v >= n) return;
  int r = v / rng;
  int vloc = v - r * rng;
  int run = 0;
  size_t idx = (size_t)(r * NSTRIPE) * rng + vloc;
  #pragma unroll 4
  for (int s = 0; s < NSTRIPE; ++s) {
    int t = Hg[idx];
    Hg[idx] = run;
    run += t;
    idx += rng;
  }
  cnt[v] = run;
}

// ---------------- 3-kernel exclusive scan (cnt -> rowp)
__global__ __launch_bounds__(1024) void k_scan_a(const int* __restrict__ cnt, int* __restrict__ rowp,
                                                 int* __restrict__ bsum, int n) {
  __shared__ int sh[1024];
  int tid = threadIdx.x;
  int idx = blockIdx.x * 1024 + tid;
  int v = (idx < n) ? cnt[idx] : 0;
  sh[tid] = v;
  __syncthreads();
  for (int offd = 1; offd < 1024; offd <<= 1) {
    int t = (tid >= offd) ? sh[tid - offd] : 0;
    __syncthreads();
    sh[tid] += t;
    __syncthreads();
  }
  if (idx < n) rowp[idx] = sh[tid] - v;  // exclusive
  if (tid == 1023) bsum[blockIdx.x] = sh[1023];
}

__global__ __launch_bounds__(128) void k_scan_b(int* __restrict__ bsum, int nb,
                                                int* __restrict__ rowp, int n) {
  __shared__ int sh[128];
  int tid = threadIdx.x;
  int v = (tid < nb) ? bsum[tid] : 0;
  sh[tid] = v;
  __syncthreads();
  for (int offd = 1; offd < 128; offd <<= 1) {
    int t = (tid >= offd) ? sh[tid - offd] : 0;
    __syncthreads();
    sh[tid] += t;
    __syncthreads();
  }
  if (tid < nb) bsum[tid] = sh[tid] - v;  // exclusive block offsets
  if (tid == 127) rowp[n] = sh[127];      // grand total
}

__global__ __launch_bounds__(1024) void k_scan_c(int* __restrict__ rowp, const int* __restrict__ bsum, int n) {
  int idx = blockIdx.x * 1024 + threadIdx.x;
  if (idx < n && blockIdx.x > 0) rowp[idx] += bsum[blockIdx.x];
}

// ---------------- pass2: placement. pos = rowp[v] + Hoff[r][st][vloc] + lds_rank
// record: {src | dir<<31, edge_weight}
__global__ __launch_bounds__(1024) void k_place(const int* __restrict__ ei, const float* __restrict__ ew,
                                                const int* __restrict__ rowp, const int* __restrict__ Hoff,
                                                int2* __restrict__ recs, int rng, int E_, int slen) {
  __shared__ int hist[MAXRNG];
  int r = blockIdx.x & (NRANGE - 1);
  int st = blockIdx.x >> 3;
  int base = r * rng;
  int tid = threadIdx.x;
  for (int t = tid; t < rng; t += 1024) hist[t] = 0;
  __syncthreads();
  const int* plane = Hoff + (size_t)(r * NSTRIPE + st) * rng;
  int e0 = st * slen;
  int e1 = min(E_, e0 + slen);
  for (int e = e0 + tid; e < e1; e += 1024) {
    int s = ei[e], d = ei[E_ + e];
    unsigned dloc = (unsigned)(d - base), sloc = (unsigned)(s - base);
    bool inA = dloc < (unsigned)rng;
    bool inB = sloc < (unsigned)rng;
    if (inA | inB) {
      int wb = __float_as_int(ew[e]);
      if (inA) {
        int lr = atomicAdd(&hist[dloc], 1);
        recs[rowp[d] + plane[dloc] + lr] = make_int2(s, wb);                    // theta = +
      }
      if (inB) {
        int lr = atomicAdd(&hist[sloc], 1);
        recs[rowp[s] + plane[sloc] + lr] = make_int2(d | (int)0x80000000, wb);  // theta = -
      }
    }
  }
}

// ---------------- weighted degree from CSR rows (no atomics) -> dinv
__global__ __launch_bounds__(256) void k_rowdeg(const int* __restrict__ rowp, const int2* __restrict__ recs,
                                                float* __restrict__ dinv, int n) {
  int wid = (blockIdx.x * 256 + threadIdx.x) >> 6;
  if (wid >= n) return;
  int lane = threadIdx.x & 63;
  int rs = rowp[wid], re = rowp[wid + 1];
  float sum = 0.f;
  for (int k = rs + lane; k < re; k += 64) sum += __int_as_float(recs[k].y);
  sum += __shfl_xor(sum, 1); sum += __shfl_xor(sum, 2);
  sum += __shfl_xor(sum, 4); sum += __shfl_xor(sum, 8);
  sum += __shfl_xor(sum, 16); sum += __shfl_xor(sum, 32);
  if (lane == 0) {
    float dg = 0.5f * sum;
    dinv[wid] = (dg > 0.f) ? rsqrtf(dg) : 0.f;
  }
}

// ---------------- per-stub normalization + phase (sequential writes)
__global__ __launch_bounds__(256) void k_norm(const int* __restrict__ rowp, const int2* __restrict__ recs,
                                              const float* __restrict__ dinv, int* __restrict__ srcs,
                                              float2* __restrict__ aw, int n) {
  int wid = (blockIdx.x * 256 + threadIdx.x) >> 6;
  if (wid >= n) return;
  int lane = threadIdx.x & 63;
  float di = dinv[wid];
  int rs = rowp[wid], re = rowp[wid + 1];
  for (int k = rs + lane; k < re; k += 64) {
    int2 r = recs[k];
    int s = r.x & 0x7fffffff;
    float w = __int_as_float(r.y);
    float nrm = di * 0.5f * w * dinv[s];
    float sn, cs;
    sincosf(PI2Q * w, &sn, &cs);
    float ar = -nrm * cs;
    float ai = (r.x < 0) ? nrm * sn : -nrm * sn;
    srcs[k] = s;
    aw[k] = make_float2(ar, ai);
  }
}

// ---------------- layer-1 hop 1 (xr==xi symmetry): one gather, 4 accumulators
__global__ __launch_bounds__(256) void k_hop_sym(
    const int* __restrict__ rowp, const int* __restrict__ srcs, const float2* __restrict__ aw,
    const float* __restrict__ PQ, float* __restrict__ U, float* __restrict__ AB, int n) {
  int wid = (blockIdx.x * 256 + threadIdx.x) >> 6;
  if (wid >= n) return;
  int lane = threadIdx.x & 63;
  int f = lane & 15, su = lane >> 4;
  int rs = rowp[wid], rend = rowp[wid + 1];
  float aA = 0.f, aB = 0.f, aC = 0.f, aD = 0.f;
  for (int k = rs + su; k < rend; k += 4) {
    int s = srcs[k];
    float2 a = aw[k];
    float wm = a.x - a.y, wp = a.x + a.y;
    float2 xv = *reinterpret_cast<const float2*>(PQ + s * 32 + 2 * f);
    aA = fmaf(wm, xv.x, aA);
    aB = fmaf(wp, xv.x, aB);
    aC = fmaf(wm, xv.y, aC);
    aD = fmaf(wp, xv.y, aD);
  }
  aA += __shfl_xor(aA, 16); aA += __shfl_xor(aA, 32);
  aB += __shfl_xor(aB, 16); aB += __shfl_xor(aB, 32);
  aC += __shfl_xor(aC, 16); aC += __shfl_xor(aC, 32);
  aD += __shfl_xor(aD, 16); aD += __shfl_xor(aD, 32);
  if (lane < 16) {
    *reinterpret_cast<float2*>(AB + wid * 32 + 2 * f) = make_float2(aA, aB);
    *reinterpret_cast<float2*>(U + wid * 32 + 2 * f) = make_float2(aC, aD);
  }
}

// ---------------- full complex hop. MODE 0: plain; 1: layer-1 epilogue -> X2; 2: final head -> y
template <int MODE>
__global__ __launch_bounds__(256) void k_hop_full(
    const int* __restrict__ rowp, const int* __restrict__ srcs, const float2* __restrict__ aw,
    const float* __restrict__ X, float* __restrict__ Y,
    const float* __restrict__ o0, const float* __restrict__ AB, const float* __restrict__ PQ,
    const float* __restrict__ D, const float* __restrict__ weff, int n) {
  int wid = (blockIdx.x * 256 + threadIdx.x) >> 6;
  if (wid >= n) return;
  int lane = threadIdx.x & 63;
  int f = lane & 15, su = lane >> 4;
  int rs = rowp[wid], rend = rowp[wid + 1];
  float aR = 0.f, aI = 0.f;
  for (int k = rs + su; k < rend; k += 4) {
    int s = srcs[k];
    float2 a = aw[k];
    float2 xv = *reinterpret_cast<const float2*>(X + s * 32 + 2 * f);
    aR = fmaf(a.x, xv.x, aR); aR = fmaf(-a.y, xv.y, aR);
    aI = fmaf(a.x, xv.y, aI); aI = fmaf(a.y, xv.x, aI);
  }
  aR += __shfl_xor(aR, 16); aR += __shfl_xor(aR, 32);
  aI += __shfl_xor(aI, 16); aI += __shfl_xor(aI, 32);
  if (MODE == 0) {
    if (lane < 16)
      *reinterpret_cast<float2*>(Y + wid * 32 + 2 * f) = make_float2(aR, aI);
  } else if (MODE == 1) {
    if (lane < 16) {
      float o = o0[wid * 16 + f];
      float2 ab = *reinterpret_cast<const float2*>(AB + wid * 32 + 2 * f);
      float q = PQ[wid * 32 + 2 * f + 1];
      *reinterpret_cast<float2*>(Y + wid * 32 + 2 * f) =
          make_float2(o + ab.x + 2.f * aR - q, o + ab.y + 2.f * aI - q);
    }
  } else {
    float c = 0.f;
    if (lane < 16) {
      float2 dv = *reinterpret_cast<const float2*>(D + wid * 32 + 2 * f);
      float zr = dv.x + 2.f * aR;
      float zi = dv.y + 2.f * aI;
      c = zr * weff[f] + zi * weff[16 + f];
    }
    c += __shfl_xor(c, 1); c += __shfl_xor(c, 2);
    c += __shfl_xor(c, 4); c += __shfl_xor(c, 8);
    if (lane == 0) Y[wid] = c + weff[32];
  }
}

// ---------------- layer-2 dense: U2 = t1'@W2[2] (complex) ; D = X2@(W2[0]-W2[2]) + t1'@W2[1] + b2
__global__ __launch_bounds__(256) void k_d2(const float* __restrict__ X2, const float* __restrict__ T1,
                                            const float* __restrict__ W2g, const float* __restrict__ b2g,
                                            float* __restrict__ U2, float* __restrict__ D, int n) {
  __shared__ float sm[1040];  // [0,768) W2 ; [768,784) b2 ; [784,1040) W2[0]-W2[2]
  int tid = threadIdx.x;
  for (int t = tid; t < 768; t += 256) sm[t] = W2g[t];
  if (tid < 16) sm[768 + tid] = b2g[tid];
  __syncthreads();
  if (tid < 256) sm[784 + tid] = sm[tid] - sm[512 + tid];
  __syncthreads();
  int i = blockIdx.x * 256 + tid;
  if (i >= n) return;
  float re[16], im[16], tr[16], ti[16];
  #pragma unroll
  for (int k = 0; k < 16; ++k) {
    float2 a = *reinterpret_cast<const float2*>(X2 + i * 32 + 2 * k);
    re[k] = a.x; im[k] = a.y;
    float2 b = *reinterpret_cast<const float2*>(T1 + i * 32 + 2 * k);
    tr[k] = b.x; ti[k] = b.y;
  }
  #pragma unroll
  for (int f = 0; f < 16; ++f) {
    float ur = 0.f, ui = 0.f;
    float dr = sm[768 + f], di = sm[768 + f];
    #pragma unroll
    for (int k = 0; k < 16; ++k) {
      float w2 = sm[512 + k * 16 + f];
      float w1 = sm[256 + k * 16 + f];
      float w02 = sm[784 + k * 16 + f];
      ur = fmaf(tr[k], w2, ur);
      ui = fmaf(ti[k], w2, ui);
      dr = fmaf(re[k], w02, dr); dr = fmaf(tr[k], w1, dr);
      di = fmaf(im[k], w02, di); di = fmaf(ti[k], w1, di);
    }
    *reinterpret_cast<float2*>(U2 + i * 32 + 2 * f) = make_float2(ur, ui);
    *reinterpret_cast<float2*>(D + i * 32 + 2 * f) = make_float2(dr, di);
  }
}

extern "C" void kernel_launch(void* const* d_in, const int* in_sizes, int n_in,
                              void* d_out, int out_size, void* d_ws, size_t ws_size,
                              hipStream_t stream) {
  const int* x = (const int*)d_in[0];
  const int* ei = (const int*)d_in[1];
  const float* ew = (const float*)d_in[2];
  const float* btab = (const float*)d_in[3];
  const float* gtab = (const float*)d_in[4];
  const float* stab = (const float*)d_in[5];
  const float* W1 = (const float*)d_in[6];
  const float* b1 = (const float*)d_in[7];
  const float* W2 = (const float*)d_in[8];
  const float* b2 = (const float*)d_in[9];
  const float* Wc = (const float*)d_in[10];
  const float* bc = (const float*)d_in[11];
  const float* Wl = (const float*)d_in[12];
  const float* bl = (const float*)d_in[13];
  float* yout = (float*)d_out;

  const int N_ = in_sizes[0] / 20;
  const int E_ = in_sizes[1] / 2;
  const int M_ = 2 * E_;
  const int rng = (N_ + NRANGE - 1) / NRANGE;      // nodes per range (<= MAXRNG)
  const int slen = (E_ + NSTRIPE - 1) / NSTRIPE;   // edges per stripe

  size_t off = 0;
  auto take = [&](size_t bytes) -> void* {
    void* p = (char*)d_ws + off;
    off += (bytes + 255) & ~(size_t)255;
    return p;
  };
  float* PQ   = (float*)take((size_t)N_ * 32 * 4);  // pairs [p,q]; reused as U2
  float* o0   = (float*)take((size_t)N_ * 16 * 4);
  float* Ubuf = (float*)take((size_t)N_ * 32 * 4);  // overlay: recs8 (first half)
  float* ABuf = (float*)take((size_t)N_ * 32 * 4);  // overlay: recs8 (second half)
  float* X2   = (float*)take((size_t)N_ * 32 * 4);
  float* dinv = (float*)take((size_t)N_ * 4);
  int* cnt    = (int*)take((size_t)N_ * 4);
  int* rowp   = (int*)take((size_t)(N_ + 1) * 4);
  int* bsum   = (int*)take(1024 * 4);
  float* weff = (float*)take(64 * 4);
  int* srcs   = (int*)take((size_t)M_ * 4);
  float2* aw  = (float2*)take((size_t)M_ * 8);
  (void)ws_size; (void)n_in; (void)out_size;

  // Overlays (lifetimes disjoint on the single stream):
  //  recs: lives [k_place .. k_norm); Ubuf/ABuf first written by k_hop_sym (later).
  //  Hg:   lives [k_hist .. k_place); srcs/aw first written by k_norm (later).
  //        size = NRANGE*NSTRIPE*rng*4 = 25.6MB <= srcs+aw (38.4MB).
  int2* recs = (int2*)Ubuf;
  int* Hg = (int*)srcs;

  int nbN = (N_ + 255) / 256;
  int nbS = (N_ + 1023) / 1024;
  int nbH = (N_ + 3) / 4;   // one wave per node
  int nbT = (N_ + 511) / 512;

  k_weff<<<1, 64, 0, stream>>>(Wc, bc, Wl, bl, weff);
  k_embed<<<nbN, 256, 0, stream>>>(x, btab, gtab, stab, W1, b1, PQ, o0, N_);

  // ---- CSR build: partitioned counting sort, zero global atomics
  k_hist<<<NRANGE * NSTRIPE, 1024, 0, stream>>>(ei, Hg, rng, E_, slen);
  k_scanH<<<nbT, 512, 0, stream>>>(Hg, cnt, rng, N_);
  k_scan_a<<<nbS, 1024, 0, stream>>>(cnt, rowp, bsum, N_);
  k_scan_b<<<1, 128, 0, stream>>>(bsum, nbS, rowp, N_);
  k_scan_c<<<nbS, 1024, 0, stream>>>(rowp, bsum, N_);
  k_place<<<NRANGE * NSTRIPE, 1024, 0, stream>>>(ei, ew, rowp, Hg, recs, rng, E_, slen);

  k_rowdeg<<<nbH, 256, 0, stream>>>(rowp, recs, dinv, N_);
  k_norm<<<nbH, 256, 0, stream>>>(rowp, recs, dinv, srcs, aw, N_);

  // layer 1
  k_hop_sym<<<nbH, 256, 0, stream>>>(rowp, srcs, aw, PQ, Ubuf, ABuf, N_);
  k_hop_full<1><<<nbH, 256, 0, stream>>>(rowp, srcs, aw, Ubuf, X2, o0, ABuf, PQ,
                                         nullptr, nullptr, N_);
  // layer 2
  k_hop_full<0><<<nbH, 256, 0, stream>>>(rowp, srcs, aw, X2, Ubuf, nullptr, nullptr,
                                         nullptr, nullptr, nullptr, N_);
  k_d2<<<nbN, 256, 0, stream>>>(X2, Ubuf, W2, b2, PQ, ABuf, N_);
  k_hop_full<2><<<nbH, 256, 0, stream>>>(rowp, srcs, aw, PQ, yout, nullptr, nullptr,
                                         nullptr, ABuf, weff, N_);
}

// Round 4
// 595.122 us; speedup vs baseline: 1.4923x; 1.0221x over previous
//
#include <hip/hip_runtime.h>
#include <math.h>

static constexpr float PI2Q = 1.57079632679489662f; // 2*pi*Q, Q=0.25
#define NRANGE 8
#define NS2 32
#define MAXRNG 13056  // LDS histogram capacity (ints); ceil(N/8) must be <= this

// ---------------- head folding: w_eff[k] = sum_j Wc[j,k]*Wl[j]; w_eff[32] = bc@Wl + bl
__global__ void k_weff(const float* __restrict__ Wc, const float* __restrict__ bc,
                       const float* __restrict__ Wl, const float* __restrict__ bl,
                       float* __restrict__ weff) {
  int k = threadIdx.x;
  if (k < 32) {
    float s = 0.f;
    #pragma unroll
    for (int j = 0; j < 32; ++j) s += Wc[j * 32 + k] * Wl[j];
    weff[k] = s;
  } else if (k == 32) {
    float s = 0.f;
    for (int j = 0; j < 32; ++j) s += bc[j] * Wl[j];
    weff[32] = s + bl[0];
  }
}

// ---------------- embedding + layer-1 dense premultiplies
__global__ __launch_bounds__(256) void k_embed(
    const int* __restrict__ x, const float* __restrict__ btab,
    const float* __restrict__ gtab, const float* __restrict__ stab,
    const float* __restrict__ W1, const float* __restrict__ b1,
    float* __restrict__ PQ, float* __restrict__ o0, int n) {
  __shared__ float sm[3184];
  // [0,1536) W1 ; [1536,1552) b1 ; [1552,1680) btab ; [1680,1744) gtab ; [1744,3184) stab
  int tid = threadIdx.x;
  for (int t = tid; t < 1536; t += 256) sm[t] = W1[t];
  if (tid < 16) sm[1536 + tid] = b1[tid];
  for (int t = tid; t < 128; t += 256) sm[1552 + t] = btab[t];
  for (int t = tid; t < 64; t += 256) sm[1680 + t] = gtab[t];
  for (int t = tid; t < 1440; t += 256) sm[1744 + t] = stab[t];
  __syncthreads();
  int i = blockIdx.x * 256 + tid;
  if (i >= n) return;
  int xr[20];
  #pragma unroll
  for (int j = 0; j < 20; ++j) xr[j] = x[i * 20 + j];
  int bi = 0;
  #pragma unroll
  for (int j = 3; j >= 0; --j) if (xr[j] == 1) bi = j;  // first match wins
  int g = xr[4];
  float h[32];
  #pragma unroll
  for (int f = 0; f < 32; ++f) {
    float s = 0.f;
    #pragma unroll
    for (int j = 0; j < 15; ++j) s += sm[1744 + j * 96 + xr[5 + j] * 32 + f];
    h[f] = (sm[1552 + bi * 32 + f] + sm[1680 + g * 32 + f] + s * (1.f / 15.f)) * (1.f / 3.f);
  }
  #pragma unroll
  for (int f = 0; f < 16; ++f) {
    float o = sm[1536 + f], p = 0.f, q = 0.f;
    #pragma unroll
    for (int k = 0; k < 32; ++k) {
      float hk = h[k];
      o = fmaf(hk, sm[k * 16 + f], o);
      p = fmaf(hk, sm[512 + k * 16 + f], p);
      q = fmaf(hk, sm[1024 + k * 16 + f], q);
    }
    o0[i * 16 + f] = o;
    PQ[i * 32 + 2 * f] = p;
    PQ[i * 32 + 2 * f + 1] = q;
  }
}

// ---------------- range histogram: stubs per range (slot-spread LDS, 8 global atomics/block)
__global__ __launch_bounds__(256) void k_rhist(const int* __restrict__ ei, int* __restrict__ rcnt,
                                               int rng, int E_) {
  __shared__ int h[8 * 16];
  int tid = threadIdx.x;
  if (tid < 128) h[tid] = 0;
  __syncthreads();
  int slot = tid & 15;
  int stride = gridDim.x * 256;
  for (int e = blockIdx.x * 256 + tid; e < E_; e += stride) {
    int s = ei[e], d = ei[E_ + e];
    atomicAdd(&h[(d / rng) * 16 + slot], 1);
    atomicAdd(&h[(s / rng) * 16 + slot], 1);
  }
  __syncthreads();
  if (tid < 8) {
    int sum = 0;
    #pragma unroll
    for (int j = 0; j < 16; ++j) sum += h[tid * 16 + j];
    atomicAdd(&rcnt[tid], sum);
  }
}

// ---------------- range bases + cursor init
__global__ void k_rbase(const int* __restrict__ rcnt, int* __restrict__ rbase, int* __restrict__ rcur) {
  if (threadIdx.x == 0) {
    int run = 0;
    for (int r = 0; r < NRANGE; ++r) { rbase[r] = run; rcur[r] = run; run += rcnt[r]; }
    rbase[NRANGE] = run;
  }
}

// ---------------- bucket stubs by range (block-level reservation, contiguous chunk writes)
__global__ __launch_bounds__(256) void k_bucket(const int* __restrict__ ei, const float* __restrict__ ew,
                                                int* __restrict__ rcur, int* __restrict__ brow,
                                                int2* __restrict__ bsw, int rng, int E_) {
  __shared__ int lcnt[NRANGE];
  __shared__ int gbase[NRANGE];
  int tid = threadIdx.x;
  if (tid < NRANGE) lcnt[tid] = 0;
  __syncthreads();
  int e0 = blockIdx.x * 1024;
  int s[4], d[4], wb[4], ra[4], rb[4], la[4], lb[4];
  #pragma unroll
  for (int j = 0; j < 4; ++j) {
    int e = e0 + j * 256 + tid;
    if (e < E_) {
      s[j] = ei[e]; d[j] = ei[E_ + e]; wb[j] = __float_as_int(ew[e]);
      ra[j] = d[j] / rng; rb[j] = s[j] / rng;
      la[j] = atomicAdd(&lcnt[ra[j]], 1);
      lb[j] = atomicAdd(&lcnt[rb[j]], 1);
    } else {
      ra[j] = -1; rb[j] = -1; s[j] = 0; d[j] = 0; wb[j] = 0; la[j] = 0; lb[j] = 0;
    }
  }
  __syncthreads();
  if (tid < NRANGE) gbase[tid] = atomicAdd(&rcur[tid], lcnt[tid]);
  __syncthreads();
  #pragma unroll
  for (int j = 0; j < 4; ++j) {
    if (ra[j] >= 0) {
      int pA = gbase[ra[j]] + la[j];
      brow[pA] = d[j];
      bsw[pA] = make_int2(s[j], wb[j]);                    // theta = +
      int pB = gbase[rb[j]] + lb[j];
      brow[pB] = s[j];
      bsw[pB] = make_int2(d[j] | (int)0x80000000, wb[j]);  // theta = -
    }
  }
}

// ---------------- per-(range,stripe) LDS histogram over the bucket
__global__ __launch_bounds__(1024) void k_hist2(const int* __restrict__ brow, const int* __restrict__ rbase,
                                                int* __restrict__ Hg, int rng) {
  __shared__ int hist[MAXRNG];
  int r = blockIdx.x & (NRANGE - 1);
  int st = blockIdx.x >> 3;
  int tid = threadIdx.x;
  for (int t = tid; t < rng; t += 1024) hist[t] = 0;
  __syncthreads();
  int b0 = rbase[r], bcnt = rbase[r + 1] - b0;
  int sl = (bcnt + NS2 - 1) / NS2;
  int k0 = b0 + st * sl, k1 = min(b0 + bcnt, k0 + sl);
  int base = r * rng;
  for (int k = k0 + tid; k < k1; k += 1024)
    atomicAdd(&hist[brow[k] - base], 1);
  __syncthreads();
  int* plane = Hg + (size_t)(r * NS2 + st) * rng;
  for (int t = tid; t < rng; t += 1024) plane[t] = hist[t];
}

// ---------------- scanH: per node, exclusive prefix across the NS2 stripes; total -> cnt
__global__ __launch_bounds__(512) void k_scanH(int* __restrict__ Hg, int* __restrict__ cnt,
                                               int rng, int n) {
  int v = blockIdx.x * 512 + threadIdx.x;
  if (v >= n) return;
  int r = v / rng;
  int vloc = v - r * rng;
  int run = 0;
  size_t idx = (size_t)(r * NS2) * rng + vloc;
  #pragma unroll 4
  for (int s = 0; s < NS2; ++s) {
    int t = Hg[idx];
    Hg[idx] = run;
    run += t;
    idx += rng;
  }
  cnt[v] = run;
}

// ---------------- 3-kernel exclusive scan (cnt -> rowp)
__global__ __launch_bounds__(1024) void k_scan_a(const int* __restrict__ cnt, int* __restrict__ rowp,
                                                 int* __restrict__ bsum, int n) {
  __shared__ int sh[1024];
  int tid = threadIdx.x;
  int idx = blockIdx.x * 1024 + tid;
  int v = (idx < n) ? cnt[idx] : 0;
  sh[tid] = v;
  __syncthreads();
  for (int offd = 1; offd < 1024; offd <<= 1) {
    int t = (tid >= offd) ? sh[tid - offd] : 0;
    __syncthreads();
    sh[tid] += t;
    __syncthreads();
  }
  if (idx < n) rowp[idx] = sh[tid] - v;  // exclusive
  if (tid == 1023) bsum[blockIdx.x] = sh[1023];
}

__global__ __launch_bounds__(128) void k_scan_b(int* __restrict__ bsum, int nb,
                                                int* __restrict__ rowp, int n) {
  __shared__ int sh[128];
  int tid = threadIdx.x;
  int v = (tid < nb) ? bsum[tid] : 0;
  sh[tid] = v;
  __syncthreads();
  for (int offd = 1; offd < 128; offd <<= 1) {
    int t = (tid >= offd) ? sh[tid - offd] : 0;
    __syncthreads();
    sh[tid] += t;
    __syncthreads();
  }
  if (tid < nb) bsum[tid] = sh[tid] - v;  // exclusive block offsets
  if (tid == 127) rowp[n] = sh[127];      // grand total
}

__global__ __launch_bounds__(1024) void k_scan_c(int* __restrict__ rowp, const int* __restrict__ bsum, int n) {
  int idx = blockIdx.x * 1024 + threadIdx.x;
  if (idx < n && blockIdx.x > 0) rowp[idx] += bsum[blockIdx.x];
}

// ---------------- placement from bucket: pos = rowp[row] + Hoff[r][st][rowloc] + lds_rank
__global__ __launch_bounds__(1024) void k_place2(const int* __restrict__ brow, const int2* __restrict__ bsw,
                                                 const int* __restrict__ rbase, const int* __restrict__ rowp,
                                                 const int* __restrict__ Hoff, int2* __restrict__ recs,
                                                 int rng) {
  __shared__ int hist[MAXRNG];
  int r = blockIdx.x & (NRANGE - 1);
  int st = blockIdx.x >> 3;
  int tid = threadIdx.x;
  for (int t = tid; t < rng; t += 1024) hist[t] = 0;
  __syncthreads();
  int b0 = rbase[r], bcnt = rbase[r + 1] - b0;
  int sl = (bcnt + NS2 - 1) / NS2;
  int k0 = b0 + st * sl, k1 = min(b0 + bcnt, k0 + sl);
  int base = r * rng;
  const int* plane = Hoff + (size_t)(r * NS2 + st) * rng;
  for (int k = k0 + tid; k < k1; k += 1024) {
    int row = brow[k];
    int rowloc = row - base;
    int lr = atomicAdd(&hist[rowloc], 1);
    recs[rowp[row] + plane[rowloc] + lr] = bsw[k];
  }
}

// ---------------- weighted degree from CSR rows (no atomics) -> dinv
__global__ __launch_bounds__(256) void k_rowdeg(const int* __restrict__ rowp, const int2* __restrict__ recs,
                                                float* __restrict__ dinv, int n) {
  int wid = (blockIdx.x * 256 + threadIdx.x) >> 6;
  if (wid >= n) return;
  int lane = threadIdx.x & 63;
  int rs = rowp[wid], re = rowp[wid + 1];
  float sum = 0.f;
  for (int k = rs + lane; k < re; k += 64) sum += __int_as_float(recs[k].y);
  sum += __shfl_xor(sum, 1); sum += __shfl_xor(sum, 2);
  sum += __shfl_xor(sum, 4); sum += __shfl_xor(sum, 8);
  sum += __shfl_xor(sum, 16); sum += __shfl_xor(sum, 32);
  if (lane == 0) {
    float dg = 0.5f * sum;
    dinv[wid] = (dg > 0.f) ? rsqrtf(dg) : 0.f;
  }
}

// ---------------- per-stub normalization + phase (sequential writes)
__global__ __launch_bounds__(256) void k_norm(const int* __restrict__ rowp, const int2* __restrict__ recs,
                                              const float* __restrict__ dinv, int* __restrict__ srcs,
                                              float2* __restrict__ aw, int n) {
  int wid = (blockIdx.x * 256 + threadIdx.x) >> 6;
  if (wid >= n) return;
  int lane = threadIdx.x & 63;
  float di = dinv[wid];
  int rs = rowp[wid], re = rowp[wid + 1];
  for (int k = rs + lane; k < re; k += 64) {
    int2 r = recs[k];
    int s = r.x & 0x7fffffff;
    float w = __int_as_float(r.y);
    float nrm = di * 0.5f * w * dinv[s];
    float sn, cs;
    sincosf(PI2Q * w, &sn, &cs);
    float ar = -nrm * cs;
    float ai = (r.x < 0) ? nrm * sn : -nrm * sn;
    srcs[k] = s;
    aw[k] = make_float2(ar, ai);
  }
}

// ---------------- layer-1 hop 1 (xr==xi symmetry): one gather, 4 accumulators
__global__ __launch_bounds__(256) void k_hop_sym(
    const int* __restrict__ rowp, const int* __restrict__ srcs, const float2* __restrict__ aw,
    const float* __restrict__ PQ, float* __restrict__ U, float* __restrict__ AB, int n) {
  int wid = (blockIdx.x * 256 + threadIdx.x) >> 6;
  if (wid >= n) return;
  int lane = threadIdx.x & 63;
  int f = lane & 15, su = lane >> 4;
  int rs = rowp[wid], rend = rowp[wid + 1];
  float aA = 0.f, aB = 0.f, aC = 0.f, aD = 0.f;
  for (int k = rs + su; k < rend; k += 4) {
    int s = srcs[k];
    float2 a = aw[k];
    float wm = a.x - a.y, wp = a.x + a.y;
    float2 xv = *reinterpret_cast<const float2*>(PQ + s * 32 + 2 * f);
    aA = fmaf(wm, xv.x, aA);
    aB = fmaf(wp, xv.x, aB);
    aC = fmaf(wm, xv.y, aC);
    aD = fmaf(wp, xv.y, aD);
  }
  aA += __shfl_xor(aA, 16); aA += __shfl_xor(aA, 32);
  aB += __shfl_xor(aB, 16); aB += __shfl_xor(aB, 32);
  aC += __shfl_xor(aC, 16); aC += __shfl_xor(aC, 32);
  aD += __shfl_xor(aD, 16); aD += __shfl_xor(aD, 32);
  if (lane < 16) {
    *reinterpret_cast<float2*>(AB + wid * 32 + 2 * f) = make_float2(aA, aB);
    *reinterpret_cast<float2*>(U + wid * 32 + 2 * f) = make_float2(aC, aD);
  }
}

// ---------------- full complex hop. MODE 0: plain; 1: layer-1 epilogue -> X2; 2: final head -> y
template <int MODE>
__global__ __launch_bounds__(256) void k_hop_full(
    const int* __restrict__ rowp, const int* __restrict__ srcs, const float2* __restrict__ aw,
    const float* __restrict__ X, float* __restrict__ Y,
    const float* __restrict__ o0, const float* __restrict__ AB, const float* __restrict__ PQ,
    const float* __restrict__ D, const float* __restrict__ weff, int n) {
  int wid = (blockIdx.x * 256 + threadIdx.x) >> 6;
  if (wid >= n) return;
  int lane = threadIdx.x & 63;
  int f = lane & 15, su = lane >> 4;
  int rs = rowp[wid], rend = rowp[wid + 1];
  float aR = 0.f, aI = 0.f;
  for (int k = rs + su; k < rend; k += 4) {
    int s = srcs[k];
    float2 a = aw[k];
    float2 xv = *reinterpret_cast<const float2*>(X + s * 32 + 2 * f);
    aR = fmaf(a.x, xv.x, aR); aR = fmaf(-a.y, xv.y, aR);
    aI = fmaf(a.x, xv.y, aI); aI = fmaf(a.y, xv.x, aI);
  }
  aR += __shfl_xor(aR, 16); aR += __shfl_xor(aR, 32);
  aI += __shfl_xor(aI, 16); aI += __shfl_xor(aI, 32);
  if (MODE == 0) {
    if (lane < 16)
      *reinterpret_cast<float2*>(Y + wid * 32 + 2 * f) = make_float2(aR, aI);
  } else if (MODE == 1) {
    if (lane < 16) {
      float o = o0[wid * 16 + f];
      float2 ab = *reinterpret_cast<const float2*>(AB + wid * 32 + 2 * f);
      float q = PQ[wid * 32 + 2 * f + 1];
      *reinterpret_cast<float2*>(Y + wid * 32 + 2 * f) =
          make_float2(o + ab.x + 2.f * aR - q, o + ab.y + 2.f * aI - q);
    }
  } else {
    float c = 0.f;
    if (lane < 16) {
      float2 dv = *reinterpret_cast<const float2*>(D + wid * 32 + 2 * f);
      float zr = dv.x + 2.f * aR;
      float zi = dv.y + 2.f * aI;
      c = zr * weff[f] + zi * weff[16 + f];
    }
    c += __shfl_xor(c, 1); c += __shfl_xor(c, 2);
    c += __shfl_xor(c, 4); c += __shfl_xor(c, 8);
    if (lane == 0) Y[wid] = c + weff[32];
  }
}

// ---------------- layer-2 dense: U2 = t1'@W2[2] (complex) ; D = X2@(W2[0]-W2[2]) + t1'@W2[1] + b2
__global__ __launch_bounds__(256) void k_d2(const float* __restrict__ X2, const float* __restrict__ T1,
                                            const float* __restrict__ W2g, const float* __restrict__ b2g,
                                            float* __restrict__ U2, float* __restrict__ D, int n) {
  __shared__ float sm[1040];  // [0,768) W2 ; [768,784) b2 ; [784,1040) W2[0]-W2[2]
  int tid = threadIdx.x;
  for (int t = tid; t < 768; t += 256) sm[t] = W2g[t];
  if (tid < 16) sm[768 + tid] = b2g[tid];
  __syncthreads();
  if (tid < 256) sm[784 + tid] = sm[tid] - sm[512 + tid];
  __syncthreads();
  int i = blockIdx.x * 256 + tid;
  if (i >= n) return;
  float re[16], im[16], tr[16], ti[16];
  #pragma unroll
  for (int k = 0; k < 16; ++k) {
    float2 a = *reinterpret_cast<const float2*>(X2 + i * 32 + 2 * k);
    re[k] = a.x; im[k] = a.y;
    float2 b = *reinterpret_cast<const float2*>(T1 + i * 32 + 2 * k);
    tr[k] = b.x; ti[k] = b.y;
  }
  #pragma unroll
  for (int f = 0; f < 16; ++f) {
    float ur = 0.f, ui = 0.f;
    float dr = sm[768 + f], di = sm[768 + f];
    #pragma unroll
    for (int k = 0; k < 16; ++k) {
      float w2 = sm[512 + k * 16 + f];
      float w1 = sm[256 + k * 16 + f];
      float w02 = sm[784 + k * 16 + f];
      ur = fmaf(tr[k], w2, ur);
      ui = fmaf(ti[k], w2, ui);
      dr = fmaf(re[k], w02, dr); dr = fmaf(tr[k], w1, dr);
      di = fmaf(im[k], w02, di); di = fmaf(ti[k], w1, di);
    }
    *reinterpret_cast<float2*>(U2 + i * 32 + 2 * f) = make_float2(ur, ui);
    *reinterpret_cast<float2*>(D + i * 32 + 2 * f) = make_float2(dr, di);
  }
}

extern "C" void kernel_launch(void* const* d_in, const int* in_sizes, int n_in,
                              void* d_out, int out_size, void* d_ws, size_t ws_size,
                              hipStream_t stream) {
  const int* x = (const int*)d_in[0];
  const int* ei = (const int*)d_in[1];
  const float* ew = (const float*)d_in[2];
  const float* btab = (const float*)d_in[3];
  const float* gtab = (const float*)d_in[4];
  const float* stab = (const float*)d_in[5];
  const float* W1 = (const float*)d_in[6];
  const float* b1 = (const float*)d_in[7];
  const float* W2 = (const float*)d_in[8];
  const float* b2 = (const float*)d_in[9];
  const float* Wc = (const float*)d_in[10];
  const float* bc = (const float*)d_in[11];
  const float* Wl = (const float*)d_in[12];
  const float* bl = (const float*)d_in[13];
  float* yout = (float*)d_out;

  const int N_ = in_sizes[0] / 20;
  const int E_ = in_sizes[1] / 2;
  const int M_ = 2 * E_;
  const int rng = (N_ + NRANGE - 1) / NRANGE;  // nodes per range (<= MAXRNG)

  size_t off = 0;
  auto take = [&](size_t bytes) -> void* {
    void* p = (char*)d_ws + off;
    off += (bytes + 255) & ~(size_t)255;
    return p;
  };
  float* PQ   = (float*)take((size_t)N_ * 32 * 4);  // pairs [p,q]; reused as U2
  float* o0   = (float*)take((size_t)N_ * 16 * 4);
  float* Ubuf = (float*)take((size_t)N_ * 32 * 4);  // overlay: recs (first half)
  float* ABuf = (float*)take((size_t)N_ * 32 * 4);  // overlay: recs (second half)
  float* X2   = (float*)take((size_t)N_ * 32 * 4);
  float* dinv = (float*)take((size_t)N_ * 4);
  int* cnt    = (int*)take((size_t)N_ * 4);
  int* rowp   = (int*)take((size_t)(N_ + 1) * 4);
  int* bsum   = (int*)take(1024 * 4);
  float* weff = (float*)take(64 * 4);
  int* rcnt   = (int*)take(NRANGE * 4);
  int* rbase  = (int*)take((NRANGE + 1) * 4);
  int* rcur   = (int*)take(NRANGE * 4);
  int* srcs   = (int*)take((size_t)M_ * 4);
  float2* aw  = (float2*)take((size_t)M_ * 8);
  (void)ws_size; (void)n_in; (void)out_size;

  // Overlays (lifetimes disjoint on the single stream):
  //  recs: [k_place2 .. k_norm); Ubuf/ABuf first written by k_hop_sym (later).
  //  Hg:   [k_hist2 .. k_place2); size = NRANGE*NS2*rng*4 = 128*N bytes <= PQ+o0 (192*N).
  //        PQ/o0 first written by k_embed, which runs AFTER k_place2.
  //  brow/bsw buckets: [k_bucket .. k_place2); srcs/aw first written by k_norm (later).
  int2* recs = (int2*)Ubuf;
  int* Hg    = (int*)PQ;
  int* brow  = (int*)srcs;
  int2* bsw  = (int2*)aw;

  int nbN = (N_ + 255) / 256;
  int nbS = (N_ + 1023) / 1024;
  int nbH = (N_ + 3) / 4;      // one wave per node
  int nbT = (N_ + 511) / 512;
  int nbB = (E_ + 1023) / 1024;

  hipMemsetAsync(rcnt, 0, NRANGE * 4, stream);

  k_weff<<<1, 64, 0, stream>>>(Wc, bc, Wl, bl, weff);

  // ---- CSR build: bucket by range, then L2-local counting sort (zero hot-path global atomics)
  k_rhist<<<512, 256, 0, stream>>>(ei, rcnt, rng, E_);
  k_rbase<<<1, 64, 0, stream>>>(rcnt, rbase, rcur);
  k_bucket<<<nbB, 256, 0, stream>>>(ei, ew, rcur, brow, bsw, rng, E_);
  k_hist2<<<NRANGE * NS2, 1024, 0, stream>>>(brow, rbase, Hg, rng);
  k_scanH<<<nbT, 512, 0, stream>>>(Hg, cnt, rng, N_);
  k_scan_a<<<nbS, 1024, 0, stream>>>(cnt, rowp, bsum, N_);
  k_scan_b<<<1, 128, 0, stream>>>(bsum, nbS, rowp, N_);
  k_scan_c<<<nbS, 1024, 0, stream>>>(rowp, bsum, N_);
  k_place2<<<NRANGE * NS2, 1024, 0, stream>>>(brow, bsw, rbase, rowp, Hg, recs, rng);

  // ---- node-wise prep (after build so Hg/bucket overlays are dead)
  k_embed<<<nbN, 256, 0, stream>>>(x, btab, gtab, stab, W1, b1, PQ, o0, N_);
  k_rowdeg<<<nbH, 256, 0, stream>>>(rowp, recs, dinv, N_);
  k_norm<<<nbH, 256, 0, stream>>>(rowp, recs, dinv, srcs, aw, N_);

  // layer 1
  k_hop_sym<<<nbH, 256, 0, stream>>>(rowp, srcs, aw, PQ, Ubuf, ABuf, N_);
  k_hop_full<1><<<nbH, 256, 0, stream>>>(rowp, srcs, aw, Ubuf, X2, o0, ABuf, PQ,
                                         nullptr, nullptr, N_);
  // layer 2
  k_hop_full<0><<<nbH, 256, 0, stream>>>(rowp, srcs, aw, X2, Ubuf, nullptr, nullptr,
                                         nullptr, nullptr, nullptr, N_);
  k_d2<<<nbN, 256, 0, stream>>>(X2, Ubuf, W2, b2, PQ, ABuf, N_);
  k_hop_full<2><<<nbH, 256, 0, stream>>>(rowp, srcs, aw, PQ, yout, nullptr, nullptr,
                                         nullptr, ABuf, weff, N_);
}

// Round 5
// 565.704 us; speedup vs baseline: 1.5699x; 1.0520x over previous
//
#include <hip/hip_runtime.h>
#include <hip/hip_fp16.h>
#include <math.h>

static constexpr float PI2Q = 1.57079632679489662f; // 2*pi*Q, Q=0.25
#define NRANGE 8
#define NS2 32
#define MAXRNG 13056  // LDS histogram capacity (ints); ceil(N/8) must be <= this

// ---------------- head folding: w_eff[k] = sum_j Wc[j,k]*Wl[j]; w_eff[32] = bc@Wl + bl
__global__ void k_weff(const float* __restrict__ Wc, const float* __restrict__ bc,
                       const float* __restrict__ Wl, const float* __restrict__ bl,
                       float* __restrict__ weff) {
  int k = threadIdx.x;
  if (k < 32) {
    float s = 0.f;
    #pragma unroll
    for (int j = 0; j < 32; ++j) s += Wc[j * 32 + k] * Wl[j];
    weff[k] = s;
  } else if (k == 32) {
    float s = 0.f;
    for (int j = 0; j < 32; ++j) s += bc[j] * Wl[j];
    weff[32] = s + bl[0];
  }
}

// ---------------- embedding + layer-1 dense premultiplies
__global__ __launch_bounds__(256) void k_embed(
    const int* __restrict__ x, const float* __restrict__ btab,
    const float* __restrict__ gtab, const float* __restrict__ stab,
    const float* __restrict__ W1, const float* __restrict__ b1,
    float* __restrict__ PQ, float* __restrict__ o0, int n) {
  __shared__ float sm[3184];
  // [0,1536) W1 ; [1536,1552) b1 ; [1552,1680) btab ; [1680,1744) gtab ; [1744,3184) stab
  int tid = threadIdx.x;
  for (int t = tid; t < 1536; t += 256) sm[t] = W1[t];
  if (tid < 16) sm[1536 + tid] = b1[tid];
  for (int t = tid; t < 128; t += 256) sm[1552 + t] = btab[t];
  for (int t = tid; t < 64; t += 256) sm[1680 + t] = gtab[t];
  for (int t = tid; t < 1440; t += 256) sm[1744 + t] = stab[t];
  __syncthreads();
  int i = blockIdx.x * 256 + tid;
  if (i >= n) return;
  int xr[20];
  #pragma unroll
  for (int j = 0; j < 20; ++j) xr[j] = x[i * 20 + j];
  int bi = 0;
  #pragma unroll
  for (int j = 3; j >= 0; --j) if (xr[j] == 1) bi = j;  // first match wins
  int g = xr[4];
  float h[32];
  #pragma unroll
  for (int f = 0; f < 32; ++f) {
    float s = 0.f;
    #pragma unroll
    for (int j = 0; j < 15; ++j) s += sm[1744 + j * 96 + xr[5 + j] * 32 + f];
    h[f] = (sm[1552 + bi * 32 + f] + sm[1680 + g * 32 + f] + s * (1.f / 15.f)) * (1.f / 3.f);
  }
  #pragma unroll
  for (int f = 0; f < 16; ++f) {
    float o = sm[1536 + f], p = 0.f, q = 0.f;
    #pragma unroll
    for (int k = 0; k < 32; ++k) {
      float hk = h[k];
      o = fmaf(hk, sm[k * 16 + f], o);
      p = fmaf(hk, sm[512 + k * 16 + f], p);
      q = fmaf(hk, sm[1024 + k * 16 + f], q);
    }
    o0[i * 16 + f] = o;
    PQ[i * 32 + 2 * f] = p;
    PQ[i * 32 + 2 * f + 1] = q;
  }
}

// ---------------- range histogram: stubs per range (slot-spread LDS, 8 global atomics/block)
__global__ __launch_bounds__(256) void k_rhist(const int* __restrict__ ei, int* __restrict__ rcnt,
                                               int rng, int E_) {
  __shared__ int h[8 * 16];
  int tid = threadIdx.x;
  if (tid < 128) h[tid] = 0;
  __syncthreads();
  int slot = tid & 15;
  int stride = gridDim.x * 256;
  for (int e = blockIdx.x * 256 + tid; e < E_; e += stride) {
    int s = ei[e], d = ei[E_ + e];
    atomicAdd(&h[(d / rng) * 16 + slot], 1);
    atomicAdd(&h[(s / rng) * 16 + slot], 1);
  }
  __syncthreads();
  if (tid < 8) {
    int sum = 0;
    #pragma unroll
    for (int j = 0; j < 16; ++j) sum += h[tid * 16 + j];
    atomicAdd(&rcnt[tid], sum);
  }
}

// ---------------- range bases + cursor init
__global__ void k_rbase(const int* __restrict__ rcnt, int* __restrict__ rbase, int* __restrict__ rcur) {
  if (threadIdx.x == 0) {
    int run = 0;
    for (int r = 0; r < NRANGE; ++r) { rbase[r] = run; rcur[r] = run; run += rcnt[r]; }
    rbase[NRANGE] = run;
  }
}

// ---------------- bucket stubs by range (block-level reservation, contiguous chunk writes)
__global__ __launch_bounds__(256) void k_bucket(const int* __restrict__ ei, const float* __restrict__ ew,
                                                int* __restrict__ rcur, int* __restrict__ brow,
                                                int2* __restrict__ bsw, int rng, int E_) {
  __shared__ int lcnt[NRANGE];
  __shared__ int gbase[NRANGE];
  int tid = threadIdx.x;
  if (tid < NRANGE) lcnt[tid] = 0;
  __syncthreads();
  int e0 = blockIdx.x * 1024;
  int s[4], d[4], wb[4], ra[4], rb[4], la[4], lb[4];
  #pragma unroll
  for (int j = 0; j < 4; ++j) {
    int e = e0 + j * 256 + tid;
    if (e < E_) {
      s[j] = ei[e]; d[j] = ei[E_ + e]; wb[j] = __float_as_int(ew[e]);
      ra[j] = d[j] / rng; rb[j] = s[j] / rng;
      la[j] = atomicAdd(&lcnt[ra[j]], 1);
      lb[j] = atomicAdd(&lcnt[rb[j]], 1);
    } else {
      ra[j] = -1; rb[j] = -1; s[j] = 0; d[j] = 0; wb[j] = 0; la[j] = 0; lb[j] = 0;
    }
  }
  __syncthreads();
  if (tid < NRANGE) gbase[tid] = atomicAdd(&rcur[tid], lcnt[tid]);
  __syncthreads();
  #pragma unroll
  for (int j = 0; j < 4; ++j) {
    if (ra[j] >= 0) {
      int pA = gbase[ra[j]] + la[j];
      brow[pA] = d[j];
      bsw[pA] = make_int2(s[j], wb[j]);                    // theta = +
      int pB = gbase[rb[j]] + lb[j];
      brow[pB] = s[j];
      bsw[pB] = make_int2(d[j] | (int)0x80000000, wb[j]);  // theta = -
    }
  }
}

// ---------------- per-(range,stripe) LDS histogram over the bucket
__global__ __launch_bounds__(1024) void k_hist2(const int* __restrict__ brow, const int* __restrict__ rbase,
                                                int* __restrict__ Hg, int rng) {
  __shared__ int hist[MAXRNG];
  int r = blockIdx.x & (NRANGE - 1);
  int st = blockIdx.x >> 3;
  int tid = threadIdx.x;
  for (int t = tid; t < rng; t += 1024) hist[t] = 0;
  __syncthreads();
  int b0 = rbase[r], bcnt = rbase[r + 1] - b0;
  int sl = (bcnt + NS2 - 1) / NS2;
  int k0 = b0 + st * sl, k1 = min(b0 + bcnt, k0 + sl);
  int base = r * rng;
  for (int k = k0 + tid; k < k1; k += 1024)
    atomicAdd(&hist[brow[k] - base], 1);
  __syncthreads();
  int* plane = Hg + (size_t)(r * NS2 + st) * rng;
  for (int t = tid; t < rng; t += 1024) plane[t] = hist[t];
}

// ---------------- scanH: per node, exclusive prefix across the NS2 stripes; total -> cnt
__global__ __launch_bounds__(512) void k_scanH(int* __restrict__ Hg, int* __restrict__ cnt,
                                               int rng, int n) {
  int v = blockIdx.x * 512 + threadIdx.x;
  if (v >= n) return;
  int r = v / rng;
  int vloc = v - r * rng;
  int run = 0;
  size_t idx = (size_t)(r * NS2) * rng + vloc;
  #pragma unroll 4
  for (int s = 0; s < NS2; ++s) {
    int t = Hg[idx];
    Hg[idx] = run;
    run += t;
    idx += rng;
  }
  cnt[v] = run;
}

// ---------------- 3-kernel exclusive scan (cnt -> rowp)
__global__ __launch_bounds__(1024) void k_scan_a(const int* __restrict__ cnt, int* __restrict__ rowp,
                                                 int* __restrict__ bsum, int n) {
  __shared__ int sh[1024];
  int tid = threadIdx.x;
  int idx = blockIdx.x * 1024 + tid;
  int v = (idx < n) ? cnt[idx] : 0;
  sh[tid] = v;
  __syncthreads();
  for (int offd = 1; offd < 1024; offd <<= 1) {
    int t = (tid >= offd) ? sh[tid - offd] : 0;
    __syncthreads();
    sh[tid] += t;
    __syncthreads();
  }
  if (idx < n) rowp[idx] = sh[tid] - v;  // exclusive
  if (tid == 1023) bsum[blockIdx.x] = sh[1023];
}

__global__ __launch_bounds__(128) void k_scan_b(int* __restrict__ bsum, int nb,
                                                int* __restrict__ rowp, int n) {
  __shared__ int sh[128];
  int tid = threadIdx.x;
  int v = (tid < nb) ? bsum[tid] : 0;
  sh[tid] = v;
  __syncthreads();
  for (int offd = 1; offd < 128; offd <<= 1) {
    int t = (tid >= offd) ? sh[tid - offd] : 0;
    __syncthreads();
    sh[tid] += t;
    __syncthreads();
  }
  if (tid < nb) bsum[tid] = sh[tid] - v;  // exclusive block offsets
  if (tid == 127) rowp[n] = sh[127];      // grand total
}

__global__ __launch_bounds__(1024) void k_scan_c(int* __restrict__ rowp, const int* __restrict__ bsum, int n) {
  int idx = blockIdx.x * 1024 + threadIdx.x;
  if (idx < n && blockIdx.x > 0) rowp[idx] += bsum[blockIdx.x];
}

// ---------------- placement from bucket: pos = rowp[row] + Hoff[r][st][rowloc] + lds_rank
__global__ __launch_bounds__(1024) void k_place2(const int* __restrict__ brow, const int2* __restrict__ bsw,
                                                 const int* __restrict__ rbase, const int* __restrict__ rowp,
                                                 const int* __restrict__ Hoff, int2* __restrict__ recs,
                                                 int rng) {
  __shared__ int hist[MAXRNG];
  int r = blockIdx.x & (NRANGE - 1);
  int st = blockIdx.x >> 3;
  int tid = threadIdx.x;
  for (int t = tid; t < rng; t += 1024) hist[t] = 0;
  __syncthreads();
  int b0 = rbase[r], bcnt = rbase[r + 1] - b0;
  int sl = (bcnt + NS2 - 1) / NS2;
  int k0 = b0 + st * sl, k1 = min(b0 + bcnt, k0 + sl);
  int base = r * rng;
  const int* plane = Hoff + (size_t)(r * NS2 + st) * rng;
  for (int k = k0 + tid; k < k1; k += 1024) {
    int row = brow[k];
    int rowloc = row - base;
    int lr = atomicAdd(&hist[rowloc], 1);
    recs[rowp[row] + plane[rowloc] + lr] = bsw[k];
  }
}

// ---------------- weighted degree from CSR rows (no atomics) -> dinv (reads recs.y as f32 weight)
__global__ __launch_bounds__(256) void k_rowdeg(const int* __restrict__ rowp, const int2* __restrict__ recs,
                                                float* __restrict__ dinv, int n) {
  int wid = (blockIdx.x * 256 + threadIdx.x) >> 6;
  if (wid >= n) return;
  int lane = threadIdx.x & 63;
  int rs = rowp[wid], re = rowp[wid + 1];
  float sum = 0.f;
  for (int k = rs + lane; k < re; k += 64) sum += __int_as_float(recs[k].y);
  sum += __shfl_xor(sum, 1); sum += __shfl_xor(sum, 2);
  sum += __shfl_xor(sum, 4); sum += __shfl_xor(sum, 8);
  sum += __shfl_xor(sum, 16); sum += __shfl_xor(sum, 32);
  if (lane == 0) {
    float dg = 0.5f * sum;
    dinv[wid] = (dg > 0.f) ? rsqrtf(dg) : 0.f;
  }
}

// ---------------- per-stub normalization + phase; packs (ar, ai_signed) as half2 into recs[k].y in place
__global__ __launch_bounds__(256) void k_norm(const int* __restrict__ rowp, int2* __restrict__ recs,
                                              const float* __restrict__ dinv, int n) {
  int wid = (blockIdx.x * 256 + threadIdx.x) >> 6;
  if (wid >= n) return;
  int lane = threadIdx.x & 63;
  float di = dinv[wid];
  int rs = rowp[wid], re = rowp[wid + 1];
  for (int k = rs + lane; k < re; k += 64) {
    int2 r = recs[k];
    int s = r.x & 0x7fffffff;
    float w = __int_as_float(r.y);
    float nrm = di * 0.5f * w * dinv[s];
    float sn, cs;
    sincosf(PI2Q * w, &sn, &cs);
    float ar = -nrm * cs;
    float ai = (r.x < 0) ? nrm * sn : -nrm * sn;
    __half2 h = __halves2half2(__float2half_rn(ar), __float2half_rn(ai));
    recs[k].y = *reinterpret_cast<int*>(&h);
  }
}

__device__ __forceinline__ void unpack_stub(long long rr, int& s, float& ar, float& ai) {
  s = ((int)rr) & 0x7fffffff;
  int wb = (int)(rr >> 32);
  __half2 h = *reinterpret_cast<__half2*>(&wb);
  ar = __low2float(h);
  ai = __high2float(h);
}

// ---------------- layer-1 hop 1 (xr==xi symmetry): one gather, 4 accumulators, 2x unrolled
__global__ __launch_bounds__(256, 8) void k_hop_sym(
    const int* __restrict__ rowp, const int2* __restrict__ recs,
    const float* __restrict__ PQ, float* __restrict__ U, float* __restrict__ AB, int n) {
  int wid = (blockIdx.x * 256 + threadIdx.x) >> 6;
  if (wid >= n) return;
  int lane = threadIdx.x & 63;
  int f = lane & 15, su = lane >> 4;
  int rs = rowp[wid], rend = rowp[wid + 1];
  float aA = 0.f, aB = 0.f, aC = 0.f, aD = 0.f;
  const long long* rq = reinterpret_cast<const long long*>(recs);
  int k = rs + su;
  for (; k + 4 < rend; k += 8) {
    long long r0 = __builtin_nontemporal_load(rq + k);
    long long r1 = __builtin_nontemporal_load(rq + k + 4);
    int s0, s1; float ar0, ai0, ar1, ai1;
    unpack_stub(r0, s0, ar0, ai0);
    unpack_stub(r1, s1, ar1, ai1);
    float2 x0 = *reinterpret_cast<const float2*>(PQ + (size_t)s0 * 32 + 2 * f);
    float2 x1 = *reinterpret_cast<const float2*>(PQ + (size_t)s1 * 32 + 2 * f);
    float wm0 = ar0 - ai0, wp0 = ar0 + ai0;
    float wm1 = ar1 - ai1, wp1 = ar1 + ai1;
    aA = fmaf(wm0, x0.x, aA); aB = fmaf(wp0, x0.x, aB);
    aC = fmaf(wm0, x0.y, aC); aD = fmaf(wp0, x0.y, aD);
    aA = fmaf(wm1, x1.x, aA); aB = fmaf(wp1, x1.x, aB);
    aC = fmaf(wm1, x1.y, aC); aD = fmaf(wp1, x1.y, aD);
  }
  if (k < rend) {
    long long r0 = __builtin_nontemporal_load(rq + k);
    int s0; float ar0, ai0;
    unpack_stub(r0, s0, ar0, ai0);
    float2 x0 = *reinterpret_cast<const float2*>(PQ + (size_t)s0 * 32 + 2 * f);
    float wm0 = ar0 - ai0, wp0 = ar0 + ai0;
    aA = fmaf(wm0, x0.x, aA); aB = fmaf(wp0, x0.x, aB);
    aC = fmaf(wm0, x0.y, aC); aD = fmaf(wp0, x0.y, aD);
  }
  aA += __shfl_xor(aA, 16); aA += __shfl_xor(aA, 32);
  aB += __shfl_xor(aB, 16); aB += __shfl_xor(aB, 32);
  aC += __shfl_xor(aC, 16); aC += __shfl_xor(aC, 32);
  aD += __shfl_xor(aD, 16); aD += __shfl_xor(aD, 32);
  if (lane < 16) {
    *reinterpret_cast<float2*>(AB + wid * 32 + 2 * f) = make_float2(aA, aB);
    *reinterpret_cast<float2*>(U + wid * 32 + 2 * f) = make_float2(aC, aD);
  }
}

// ---------------- full complex hop. MODE 0: plain; 1: layer-1 epilogue -> X2; 2: final head -> y
template <int MODE>
__global__ __launch_bounds__(256, 8) void k_hop_full(
    const int* __restrict__ rowp, const int2* __restrict__ recs,
    const float* __restrict__ X, float* __restrict__ Y,
    const float* __restrict__ o0, const float* __restrict__ AB, const float* __restrict__ PQ,
    const float* __restrict__ D, const float* __restrict__ weff, int n) {
  int wid = (blockIdx.x * 256 + threadIdx.x) >> 6;
  if (wid >= n) return;
  int lane = threadIdx.x & 63;
  int f = lane & 15, su = lane >> 4;
  int rs = rowp[wid], rend = rowp[wid + 1];
  float aR = 0.f, aI = 0.f;
  const long long* rq = reinterpret_cast<const long long*>(recs);
  int k = rs + su;
  for (; k + 4 < rend; k += 8) {
    long long r0 = __builtin_nontemporal_load(rq + k);
    long long r1 = __builtin_nontemporal_load(rq + k + 4);
    int s0, s1; float ar0, ai0, ar1, ai1;
    unpack_stub(r0, s0, ar0, ai0);
    unpack_stub(r1, s1, ar1, ai1);
    float2 x0 = *reinterpret_cast<const float2*>(X + (size_t)s0 * 32 + 2 * f);
    float2 x1 = *reinterpret_cast<const float2*>(X + (size_t)s1 * 32 + 2 * f);
    aR = fmaf(ar0, x0.x, aR); aR = fmaf(-ai0, x0.y, aR);
    aI = fmaf(ar0, x0.y, aI); aI = fmaf(ai0, x0.x, aI);
    aR = fmaf(ar1, x1.x, aR); aR = fmaf(-ai1, x1.y, aR);
    aI = fmaf(ar1, x1.y, aI); aI = fmaf(ai1, x1.x, aI);
  }
  if (k < rend) {
    long long r0 = __builtin_nontemporal_load(rq + k);
    int s0; float ar0, ai0;
    unpack_stub(r0, s0, ar0, ai0);
    float2 x0 = *reinterpret_cast<const float2*>(X + (size_t)s0 * 32 + 2 * f);
    aR = fmaf(ar0, x0.x, aR); aR = fmaf(-ai0, x0.y, aR);
    aI = fmaf(ar0, x0.y, aI); aI = fmaf(ai0, x0.x, aI);
  }
  aR += __shfl_xor(aR, 16); aR += __shfl_xor(aR, 32);
  aI += __shfl_xor(aI, 16); aI += __shfl_xor(aI, 32);
  if (MODE == 0) {
    if (lane < 16)
      *reinterpret_cast<float2*>(Y + wid * 32 + 2 * f) = make_float2(aR, aI);
  } else if (MODE == 1) {
    if (lane < 16) {
      float o = o0[wid * 16 + f];
      float2 ab = *reinterpret_cast<const float2*>(AB + wid * 32 + 2 * f);
      float q = PQ[wid * 32 + 2 * f + 1];
      *reinterpret_cast<float2*>(Y + wid * 32 + 2 * f) =
          make_float2(o + ab.x + 2.f * aR - q, o + ab.y + 2.f * aI - q);
    }
  } else {
    float c = 0.f;
    if (lane < 16) {
      float2 dv = *reinterpret_cast<const float2*>(D + wid * 32 + 2 * f);
      float zr = dv.x + 2.f * aR;
      float zi = dv.y + 2.f * aI;
      c = zr * weff[f] + zi * weff[16 + f];
    }
    c += __shfl_xor(c, 1); c += __shfl_xor(c, 2);
    c += __shfl_xor(c, 4); c += __shfl_xor(c, 8);
    if (lane == 0) Y[wid] = c + weff[32];
  }
}

// ---------------- layer-2 dense: U2 = t1'@W2[2] (complex) ; D = X2@(W2[0]-W2[2]) + t1'@W2[1] + b2
__global__ __launch_bounds__(256) void k_d2(const float* __restrict__ X2, const float* __restrict__ T1,
                                            const float* __restrict__ W2g, const float* __restrict__ b2g,
                                            float* __restrict__ U2, float* __restrict__ D, int n) {
  __shared__ float sm[1040];  // [0,768) W2 ; [768,784) b2 ; [784,1040) W2[0]-W2[2]
  int tid = threadIdx.x;
  for (int t = tid; t < 768; t += 256) sm[t] = W2g[t];
  if (tid < 16) sm[768 + tid] = b2g[tid];
  __syncthreads();
  if (tid < 256) sm[784 + tid] = sm[tid] - sm[512 + tid];
  __syncthreads();
  int i = blockIdx.x * 256 + tid;
  if (i >= n) return;
  float re[16], im[16], tr[16], ti[16];
  #pragma unroll
  for (int k = 0; k < 16; ++k) {
    float2 a = *reinterpret_cast<const float2*>(X2 + i * 32 + 2 * k);
    re[k] = a.x; im[k] = a.y;
    float2 b = *reinterpret_cast<const float2*>(T1 + i * 32 + 2 * k);
    tr[k] = b.x; ti[k] = b.y;
  }
  #pragma unroll
  for (int f = 0; f < 16; ++f) {
    float ur = 0.f, ui = 0.f;
    float dr = sm[768 + f], di = sm[768 + f];
    #pragma unroll
    for (int k = 0; k < 16; ++k) {
      float w2 = sm[512 + k * 16 + f];
      float w1 = sm[256 + k * 16 + f];
      float w02 = sm[784 + k * 16 + f];
      ur = fmaf(tr[k], w2, ur);
      ui = fmaf(ti[k], w2, ui);
      dr = fmaf(re[k], w02, dr); dr = fmaf(tr[k], w1, dr);
      di = fmaf(im[k], w02, di); di = fmaf(ti[k], w1, di);
    }
    *reinterpret_cast<float2*>(U2 + i * 32 + 2 * f) = make_float2(ur, ui);
    *reinterpret_cast<float2*>(D + i * 32 + 2 * f) = make_float2(dr, di);
  }
}

extern "C" void kernel_launch(void* const* d_in, const int* in_sizes, int n_in,
                              void* d_out, int out_size, void* d_ws, size_t ws_size,
                              hipStream_t stream) {
  const int* x = (const int*)d_in[0];
  const int* ei = (const int*)d_in[1];
  const float* ew = (const float*)d_in[2];
  const float* btab = (const float*)d_in[3];
  const float* gtab = (const float*)d_in[4];
  const float* stab = (const float*)d_in[5];
  const float* W1 = (const float*)d_in[6];
  const float* b1 = (const float*)d_in[7];
  const float* W2 = (const float*)d_in[8];
  const float* b2 = (const float*)d_in[9];
  const float* Wc = (const float*)d_in[10];
  const float* bc = (const float*)d_in[11];
  const float* Wl = (const float*)d_in[12];
  const float* bl = (const float*)d_in[13];
  float* yout = (float*)d_out;

  const int N_ = in_sizes[0] / 20;
  const int E_ = in_sizes[1] / 2;
  const int M_ = 2 * E_;
  const int rng = (N_ + NRANGE - 1) / NRANGE;  // nodes per range (<= MAXRNG)

  size_t off = 0;
  auto take = [&](size_t bytes) -> void* {
    void* p = (char*)d_ws + off;
    off += (bytes + 255) & ~(size_t)255;
    return p;
  };
  float* PQ   = (float*)take((size_t)N_ * 32 * 4);  // pairs [p,q]; reused as U2
  float* o0   = (float*)take((size_t)N_ * 16 * 4);
  float* Ubuf = (float*)take((size_t)N_ * 32 * 4);
  float* ABuf = (float*)take((size_t)N_ * 32 * 4);
  float* X2   = (float*)take((size_t)N_ * 32 * 4);
  float* dinv = (float*)take((size_t)N_ * 4);
  int* cnt    = (int*)take((size_t)N_ * 4);
  int* rowp   = (int*)take((size_t)(N_ + 1) * 4);
  int* bsum   = (int*)take(1024 * 4);
  float* weff = (float*)take(64 * 4);
  int* rcnt   = (int*)take(NRANGE * 4);
  int* rbase  = (int*)take((NRANGE + 1) * 4);
  int* rcur   = (int*)take(NRANGE * 4);
  int* brow   = (int*)take((size_t)M_ * 4);   // bucket rows   (dead after k_place2)
  int2* bsw   = (int2*)take((size_t)M_ * 8);  // bucket payload(dead after k_place2)
  (void)ws_size; (void)n_in; (void)out_size;

  // Overlays (lifetimes disjoint on the single stream):
  //  recs: [k_place2 .. last hop]; holds (src|dir, w) then in-place (src|dir, half2(ar,ai)).
  //        Lives in ws dedicated region? No: recs persists through ALL hops now, so it gets
  //        its own storage — reuse brow/bsw? brow/bsw die at place2 but recs is WRITTEN by
  //        place2... recs must not alias its own input. Use a separate region: Ubuf/ABuf
  //        would alias hop outputs. So recs aliases bsw only AFTER... -> give recs the
  //        brow+bsw region is unsafe (place2 reads bsw while writing recs).
  //  Solution: recs gets its own allocation below.
  int2* recs = (int2*)take((size_t)M_ * 8);
  //  Hg: [k_hist2 .. k_place2); size = NRANGE*NS2*rng*4 = 128*N bytes <= PQ+o0 (192*N).
  //      PQ/o0 first written by k_embed, which runs AFTER k_place2.
  int* Hg = (int*)PQ;

  int nbN = (N_ + 255) / 256;
  int nbS = (N_ + 1023) / 1024;
  int nbH = (N_ + 3) / 4;      // one wave per node
  int nbT = (N_ + 511) / 512;
  int nbB = (E_ + 1023) / 1024;

  hipMemsetAsync(rcnt, 0, NRANGE * 4, stream);

  k_weff<<<1, 64, 0, stream>>>(Wc, bc, Wl, bl, weff);

  // ---- CSR build: bucket by range, then L2-local counting sort (zero hot-path global atomics)
  k_rhist<<<512, 256, 0, stream>>>(ei, rcnt, rng, E_);
  k_rbase<<<1, 64, 0, stream>>>(rcnt, rbase, rcur);
  k_bucket<<<nbB, 256, 0, stream>>>(ei, ew, rcur, brow, bsw, rng, E_);
  k_hist2<<<NRANGE * NS2, 1024, 0, stream>>>(brow, rbase, Hg, rng);
  k_scanH<<<nbT, 512, 0, stream>>>(Hg, cnt, rng, N_);
  k_scan_a<<<nbS, 1024, 0, stream>>>(cnt, rowp, bsum, N_);
  k_scan_b<<<1, 128, 0, stream>>>(bsum, nbS, rowp, N_);
  k_scan_c<<<nbS, 1024, 0, stream>>>(rowp, bsum, N_);
  k_place2<<<NRANGE * NS2, 1024, 0, stream>>>(brow, bsw, rbase, rowp, Hg, recs, rng);

  // ---- node-wise prep (after build so Hg overlay on PQ is dead)
  k_embed<<<nbN, 256, 0, stream>>>(x, btab, gtab, stab, W1, b1, PQ, o0, N_);
  k_rowdeg<<<nbH, 256, 0, stream>>>(rowp, recs, dinv, N_);
  k_norm<<<nbH, 256, 0, stream>>>(rowp, recs, dinv, N_);

  // layer 1
  k_hop_sym<<<nbH, 256, 0, stream>>>(rowp, recs, PQ, Ubuf, ABuf, N_);
  k_hop_full<1><<<nbH, 256, 0, stream>>>(rowp, recs, Ubuf, X2, o0, ABuf, PQ,
                                         nullptr, nullptr, N_);
  // layer 2
  k_hop_full<0><<<nbH, 256, 0, stream>>>(rowp, recs, X2, Ubuf, nullptr, nullptr,
                                         nullptr, nullptr, nullptr, N_);
  k_d2<<<nbN, 256, 0, stream>>>(X2, Ubuf, W2, b2, PQ, ABuf, N_);
  k_hop_full<2><<<nbH, 256, 0, stream>>>(rowp, recs, PQ, yout, nullptr, nullptr,
                                         nullptr, ABuf, weff, N_);
}